// Round 2
// 918.735 us; speedup vs baseline: 1.0824x; 1.0824x over previous
//
#include <hip/hip_runtime.h>
#include <hip/hip_bf16.h>
#include <math.h>

// Problem constants
#define B_ 32
#define S_ 64
#define MV_ 30
#define V_ 20000
#define E_ 256
#define H_ 512
#define L_ 128
#define H3_ 1536
#define BS_ 2048   // B*S
#define NB4 256    // k4 grid blocks (persistent, co-resident; 8 groups x 32)
#define FPAD 32    // flag padding (ints) -> one flag per 128B line
#define NEG7 -3.0e38f

typedef __attribute__((ext_vector_type(8))) short short8v;  // 8 bf16 (4 VGPRs)
typedef __attribute__((ext_vector_type(4))) float f32x4;
typedef unsigned long long ull_;

// ---------------------------------------------------------------------------
// K12: blocks [0,2048): k1 multi-hot embed body (verbatim);
//      blocks [2048,2112): k2 h0 body (grouped packing for new k4);
//      block 2112: zero-init k4 flags.
// h0 layout: hglob[(b>>2)*2048 + j*4 + (b&3)]  (group-major, unit, batch-in-group)
// ---------------------------------------------------------------------------
__global__ __launch_bounds__(256) void k12(const int* __restrict__ seq,
                                           const float* __restrict__ Ew,
                                           const float* __restrict__ z,
                                           const float* __restrict__ Wl,
                                           const float* __restrict__ bl,
                                           double* __restrict__ emb,
                                           double* __restrict__ hglob,
                                           int* __restrict__ flags) {
    __shared__ int sidx[MV_];
    int bid = blockIdx.x;
    int t = threadIdx.x;
    if (bid < BS_) {
        int row = bid;
        if (t < MV_) sidx[t] = seq[row * MV_ + t];
        __syncthreads();
        double acc = 0.0;
        for (int i = 0; i < MV_; ++i) {
            int id = sidx[i];
            if (id == 0) continue;
            bool dup = false;
            for (int q = 0; q < i; ++q) dup = dup || (sidx[q] == id);
            if (!dup) acc += (double)Ew[(size_t)id * E_ + t];
        }
        emb[(size_t)row * E_ + t] = tanh(acc);
    } else if (bid < BS_ + 64) {
        int o = (bid - BS_) * 256 + t;   // < 16384
        int b = o >> 9;
        int j = o & 511;
        const float4* zr = (const float4*)(z + (size_t)b * L_);
        const float4* wr = (const float4*)(Wl + (size_t)j * L_);
        double acc = (double)bl[j];
#pragma unroll
        for (int k = 0; k < L_ / 4; ++k) {
            float4 a = zr[k];
            float4 w = wr[k];
            acc += (double)a.x * (double)w.x + (double)a.y * (double)w.y
                 + (double)a.z * (double)w.z + (double)a.w * (double)w.w;
        }
        hglob[(size_t)(b >> 2) * 2048 + j * 4 + (b & 3)] = acc;
    } else {
        for (int i = t; i < NB4 * FPAD; i += 256) flags[i] = 0;
    }
}

// ---------------------------------------------------------------------------
// K3: Gi = emb @ W_ih^T + b_ih  (2048x1536, K=256), f64. 64x64 tile, 4x4/thread.
//     Output PACKED for k4: gi_p[(((s*512 + unit)*3 + gate)*32 + b)]
// ---------------------------------------------------------------------------
__global__ __launch_bounds__(256) void k3_gi(const double* __restrict__ A,
                                             const float* __restrict__ Bm,
                                             const float* __restrict__ bih,
                                             double* __restrict__ gi) {
    __shared__ double As[16][66];
    __shared__ double Bs[16][66];
    int t = threadIdx.x;
    int n0 = blockIdx.x * 64;   // 24
    int m0 = blockIdx.y * 64;   // 32
    int tx = t & 15, ty = t >> 4;
    int ml = t >> 2;
    int kl = (t & 3) * 4;
    double acc[4][4];
#pragma unroll
    for (int i = 0; i < 4; ++i)
#pragma unroll
        for (int j = 0; j < 4; ++j) acc[i][j] = 0.0;

    for (int kt = 0; kt < 256; kt += 16) {
        double4 av = *(const double4*)(A + (size_t)(m0 + ml) * 256 + kt + kl);
        float4 bv = *(const float4*)(Bm + (size_t)(n0 + ml) * 256 + kt + kl);
        As[kl + 0][ml] = av.x; As[kl + 1][ml] = av.y; As[kl + 2][ml] = av.z; As[kl + 3][ml] = av.w;
        Bs[kl + 0][ml] = (double)bv.x; Bs[kl + 1][ml] = (double)bv.y;
        Bs[kl + 2][ml] = (double)bv.z; Bs[kl + 3][ml] = (double)bv.w;
        __syncthreads();
#pragma unroll
        for (int kk = 0; kk < 16; ++kk) {
            double2 a01 = *(const double2*)&As[kk][ty * 4];
            double2 a23 = *(const double2*)&As[kk][ty * 4 + 2];
            double2 b01 = *(const double2*)&Bs[kk][tx * 4];
            double2 b23 = *(const double2*)&Bs[kk][tx * 4 + 2];
            double am[4] = {a01.x, a01.y, a23.x, a23.y};
            double bn[4] = {b01.x, b01.y, b23.x, b23.y};
#pragma unroll
            for (int i = 0; i < 4; ++i)
#pragma unroll
                for (int j = 0; j < 4; ++j) acc[i][j] += am[i] * bn[j];
        }
        __syncthreads();
    }
#pragma unroll
    for (int i = 0; i < 4; ++i) {
        int m = m0 + ty * 4 + i;
        int bb = m >> 6, ss = m & 63;
#pragma unroll
        for (int j = 0; j < 4; ++j) {
            int n = n0 + tx * 4 + j;
            int g = n >> 9, u = n & 511;
            gi[(((size_t)(ss * 512 + u)) * 3 + g) * 32 + bb] = acc[i][j] + (double)bih[n];
        }
    }
}

// ---------------------------------------------------------------------------
// K4 (round-11): persistent cooperative GRU, batch-partitioned sync groups.
//   256 blocks x 256 thr = 1 block/CU (LDS-forced), all 256 CUs.
//   Group g = bid&7 (8 groups x 32 blocks); group owns batches 4g..4g+3.
//   Block beta = bid>>3 owns units beta*16..beta*16+15; W_hh slice (f32) in LDS.
//   FIX vs round-10: LDS additive shift is now the INJECTIVE cumulative form
//   (k>>5)*4 — the old ((k>>5)&3)*4 collided across 128-k super-span
//   boundaries (span-3 tail and span-4 head both landed on [128,139]),
//   clobbering staged W_hh/h entries. ks-group spacing mod 32 banks is
//   unchanged (h: 1056B -> bank offset 8, conflict-free; W: 144B -> 4).
// ---------------------------------------------------------------------------
#define WROW 580   // f32 row stride for wlds (512 + 64 shift pad + 4)
__global__ __launch_bounds__(256, 1) void k4_gru(const double* __restrict__ gi,
                                                 const float* __restrict__ whh,
                                                 const float* __restrict__ bhh,
                                                 const int* __restrict__ length,
                                                 double* __restrict__ hglob,
                                                 float* __restrict__ outs,
                                                 int* __restrict__ flags) {
    __shared__ float  wl[48 * WROW];        // 16 units x 3 gates, ~108.8 KB
    __shared__ double hl[2112];             // group h: idx = e + (e>>7)*4, e=u*4+b
    __shared__ double part[4][16][3][4];    // [wave][ul][gate][batch] partials

    int t = threadIdx.x;
    int wv = t >> 6;
    int lane = t & 63;
    int bid = blockIdx.x;
    int g = bid & 7;          // group (maps to one XCD under round-robin; perf hint only)
    int beta = bid >> 3;      // block-in-group 0..31

    // ---- stage W_hh slice (16 units x 3 gates x 512), injective bank-shift ----
    for (int i = t; i < 6144; i += 256) {
        int r  = i >> 7;            // 0..47  (= ul*3 + gate)
        int c4 = i & 127;
        int uu = r / 3, gg = r - uu * 3;
        int row = (gg << 9) + beta * 16 + uu;       // W_hh row (gate*512 + unit)
        float4 v = *(const float4*)&whh[(size_t)row * 512 + c4 * 4];
        int k = c4 * 4;
        *(float4*)&wl[r * WROW + k + ((k >> 5) << 2)] = v;
    }
    // ---- initial h (parity 0), group-local 16KB ----
    {
        const double* hg0 = hglob + (size_t)g * 2048;
#pragma unroll
        for (int j = 0; j < 8; ++j) {
            int e = t + j * 256;
            hl[e + ((e >> 7) << 2)] = hg0[e];
        }
    }
    __syncthreads();

    // wave0 per-lane elementwise state: lane = (u2 0..15, b2 0..3)
    int u2 = lane >> 2, b2 = lane & 3;
    int u_g = beta * 16 + u2;      // global unit
    int b_g = g * 4 + b2;          // global batch
    double gr = 0.0, gz = 0.0, gn = 0.0, bhr_ = 0.0, bhz_ = 0.0, bhn_ = 0.0;
    int len = 0;
    int hvidx = u_g * 4 + b2 + ((u_g >> 5) << 2);
    if (wv == 0) {
        bhr_ = (double)bhh[u_g];
        bhz_ = (double)bhh[u_g + 512];
        bhn_ = (double)bhh[u_g + 1024];
        len = length[b_g];
        size_t gb = ((size_t)u_g * 3) * 32 + b_g;
        gr = gi[gb]; gz = gi[gb + 32]; gn = gi[gb + 64];
    }

    // matvec lane mapping: (ul, ks); wave wv covers k in [wv*128, wv*128+128)
    int ul = lane >> 2, ks = lane & 3;
    const float*  wr0 = &wl[(ul * 3 + 0) * WROW + wv * 128 + ks * 32 + ((wv * 4 + ks) << 2)];
    const float*  wr1 = wr0 + WROW;
    const float*  wr2 = wr0 + 2 * WROW;
    const double* hr  = &hl[(wv * 128 + ks * 32) * 4 + ((wv * 4 + ks) << 2)];
    int myflag = (g * 32 + (lane & 31)) * FPAD;   // lane<32 polls block (lane) of group

    for (int s = 0; s < S_; ++s) {
        double a0[4] = {0, 0, 0, 0}, a1[4] = {0, 0, 0, 0}, a2[4] = {0, 0, 0, 0};
#pragma unroll
        for (int c = 0; c < 8; ++c) {
            float4 w0 = *(const float4*)(wr0 + c * 4);
            float4 w1 = *(const float4*)(wr1 + c * 4);
            float4 w2 = *(const float4*)(wr2 + c * 4);
            float f0[4] = {w0.x, w0.y, w0.z, w0.w};
            float f1[4] = {w1.x, w1.y, w1.z, w1.w};
            float f2[4] = {w2.x, w2.y, w2.z, w2.w};
#pragma unroll
            for (int j = 0; j < 4; ++j) {
                const double* hp = hr + (c * 4 + j) * 4;
                double2 hA = *(const double2*)hp;
                double2 hB = *(const double2*)(hp + 2);
                double d0 = (double)f0[j], d1 = (double)f1[j], d2 = (double)f2[j];
                a0[0] += hA.x * d0; a0[1] += hA.y * d0; a0[2] += hB.x * d0; a0[3] += hB.y * d0;
                a1[0] += hA.x * d1; a1[1] += hA.y * d1; a1[2] += hB.x * d1; a1[3] += hB.y * d1;
                a2[0] += hA.x * d2; a2[1] += hA.y * d2; a2[2] += hB.x * d2; a2[3] += hB.y * d2;
            }
        }
        // reduce over ks (lanes xor 1, 2)
#pragma unroll
        for (int b = 0; b < 4; ++b) {
            a0[b] += __shfl_xor(a0[b], 1); a0[b] += __shfl_xor(a0[b], 2);
            a1[b] += __shfl_xor(a1[b], 1); a1[b] += __shfl_xor(a1[b], 2);
            a2[b] += __shfl_xor(a2[b], 1); a2[b] += __shfl_xor(a2[b], 2);
        }
        if (ks == 0) {
#pragma unroll
            for (int b = 0; b < 4; ++b) {
                part[wv][ul][0][b] = a0[b];
                part[wv][ul][1][b] = a1[b];
                part[wv][ul][2][b] = a2[b];
            }
        }
        __syncthreads();   // S1: partials visible

        if (wv == 0) {
            double s0 = part[0][u2][0][b2] + part[1][u2][0][b2] + part[2][u2][0][b2] + part[3][u2][0][b2];
            double s1 = part[0][u2][1][b2] + part[1][u2][1][b2] + part[2][u2][1][b2] + part[3][u2][1][b2];
            double s2 = part[0][u2][2][b2] + part[1][u2][2][b2] + part[2][u2][2][b2] + part[3][u2][2][b2];
            double r  = 1.0 / (1.0 + exp(-(gr + s0 + bhr_)));
            double zt = 1.0 / (1.0 + exp(-(gz + s1 + bhz_)));
            double n  = tanh(gn + r * (s2 + bhn_));
            double hv = hl[hvidx];                    // safe: no hl writer until own flag set
            double hn_ = (1.0 - zt) * n + zt * hv;
            outs[(size_t)(b_g * 64 + s) * H_ + u_g] = (s < len) ? (float)hn_ : 0.0f;
            if (s < S_ - 1) {
                double* hdst = hglob + ((size_t)((s + 1) & 1)) * 16384 + (size_t)g * 2048;
                // (beta*16+u2)*4 + b2 == beta*64 + lane -> fully coalesced 512B store
                __hip_atomic_store((ull_*)&hdst[beta * 64 + lane],
                                   __builtin_bit_cast(ull_, hn_),
                                   __ATOMIC_RELAXED, __HIP_MEMORY_SCOPE_AGENT);
                if (lane == 0)
                    __hip_atomic_store(&flags[(g * 32 + beta) * FPAD], s + 1,
                                       __ATOMIC_RELEASE, __HIP_MEMORY_SCOPE_AGENT);
            }
        }
        if (s == S_ - 1) break;

        // ---- poll the 32 flags of this group (all waves; lane<32 active) ----
        {
            bool seen = (lane >= 32);
            while (!__all(seen)) {
                if (!seen)
                    seen = __hip_atomic_load(&flags[myflag], __ATOMIC_RELAXED,
                                             __HIP_MEMORY_SCOPE_AGENT) >= s + 1;
                if (!__all(seen)) __builtin_amdgcn_s_sleep(1);
            }
        }
        asm volatile("" ::: "memory");
        // ---- restage group h (16KB, coalesced 8B/lane x 8) ----
        {
            const ull_* hgu =
                (const ull_*)(hglob + ((size_t)((s + 1) & 1)) * 16384 + (size_t)g * 2048);
            ull_ tmp[8];
#pragma unroll
            for (int j = 0; j < 8; ++j)
                tmp[j] = __hip_atomic_load(&hgu[t + j * 256],
                                           __ATOMIC_RELAXED, __HIP_MEMORY_SCOPE_AGENT);
            ull_* hlu = (ull_*)hl;
#pragma unroll
            for (int j = 0; j < 8; ++j) {
                int e = t + j * 256;
                hlu[e + ((e >> 7) << 2)] = tmp[j];
            }
        }
        // gi prefetch for s+1 (wave0; overlaps with S2 + next matvec issue)
        if (wv == 0) {
            size_t gb = ((size_t)((s + 1) * 512 + u_g) * 3) * 32 + b_g;
            gr = gi[gb]; gz = gi[gb + 32]; gn = gi[gb + 64];
        }
        __syncthreads();   // S2: hl ready for next step
    }
}

// ---------------------------------------------------------------------------
// bf16 helpers + fused prep kernel: blocks [0,5000) convert W_out -> W16,
// blocks [5000,5512) convert outs -> A16.
// ---------------------------------------------------------------------------
__device__ __forceinline__ unsigned short f2b_(float x) {
    unsigned u = __builtin_bit_cast(unsigned, x);
    return (unsigned short)((u + 0x7FFFu + ((u >> 16) & 1u)) >> 16);   // RNE
}
__device__ __forceinline__ short8v pack8_(float4 a, float4 b) {
    short8v r;
    r[0] = (short)f2b_(a.x); r[1] = (short)f2b_(a.y);
    r[2] = (short)f2b_(a.z); r[3] = (short)f2b_(a.w);
    r[4] = (short)f2b_(b.x); r[5] = (short)f2b_(b.y);
    r[6] = (short)f2b_(b.z); r[7] = (short)f2b_(b.w);
    return r;
}
__global__ __launch_bounds__(256) void k_prep2(const float* __restrict__ Wsrc,
                                               const float* __restrict__ Asrc,
                                               short* __restrict__ W16,
                                               short* __restrict__ A16) {
    int bid = blockIdx.x, t = threadIdx.x;
    if (bid < 5000) {
        int i = bid * 256 + t;               // < 1,280,000
        float4 a = *(const float4*)&Wsrc[(size_t)i * 8];
        float4 b = *(const float4*)&Wsrc[(size_t)i * 8 + 4];
        *(short8v*)&W16[(size_t)i * 8] = pack8_(a, b);
    } else {
        int i = (bid - 5000) * 256 + t;      // < 131072
        float4 a = *(const float4*)&Asrc[(size_t)i * 8];
        float4 b = *(const float4*)&Asrc[(size_t)i * 8 + 4];
        *(short8v*)&A16[(size_t)i * 8] = pack8_(a, b);
    }
}

// ---------------------------------------------------------------------------
// K5: p = sigmoid(outs_bf16 @ W_bf16^T + b_out), bf16 MFMA. BK=64.
//     128x128 tile, 4 waves (2x2 of 64x64), LDS stride 72.
// ---------------------------------------------------------------------------
#define LDK5 72
__global__ __launch_bounds__(256, 2) void k5_mfma(const short* __restrict__ A16,  // 2048x512 bf16
                                                  const short* __restrict__ W16,  // 20000x512 bf16
                                                  const float* __restrict__ bo,
                                                  float* __restrict__ pOut) {
    __shared__ short As[128 * LDK5];   // 18.4KB
    __shared__ short Bs[128 * LDK5];
    int t = threadIdx.x;
    int bid = blockIdx.x;                       // 0..2511
    int swz = (bid & 7) * 314 + (bid >> 3);     // XCD swizzle (bijective, 2512=8*314)
    int m0 = (swz & 15) * 128;
    int n0 = (swz >> 4) * 128;
    int lane = t & 63, wv = t >> 6;
    int wr = wv >> 1, wc = wv & 1;              // wave -> 64x64 quadrant
    int ml = t >> 1;                            // 0..127 (staging row)
    int kl = (t & 1) * 32;                      // 0 or 32 (staging k-offset)

    const short* Arow = A16 + (size_t)(m0 + ml) * H_ + kl;
    int vrow = n0 + ml;
    bool vok = vrow < V_;
    const short* Wrow = W16 + (size_t)(vok ? vrow : 0) * H_ + kl;
    short8v zz = (short8v){0, 0, 0, 0, 0, 0, 0, 0};

    f32x4 acc[4][4];
#pragma unroll
    for (int i = 0; i < 4; ++i)
#pragma unroll
        for (int j = 0; j < 4; ++j) acc[i][j] = (f32x4){0.f, 0.f, 0.f, 0.f};

    int ko = lane >> 4;       // 0..3 (k-group of 8)
    int rr = lane & 15;       // fragment row/col

    for (int kt = 0; kt < H_; kt += 64) {
        short8v a0 = *(const short8v*)(Arow + kt);
        short8v a1 = *(const short8v*)(Arow + kt + 8);
        short8v a2 = *(const short8v*)(Arow + kt + 16);
        short8v a3 = *(const short8v*)(Arow + kt + 24);
        short8v b0 = vok ? *(const short8v*)(Wrow + kt) : zz;
        short8v b1 = vok ? *(const short8v*)(Wrow + kt + 8) : zz;
        short8v b2 = vok ? *(const short8v*)(Wrow + kt + 16) : zz;
        short8v b3 = vok ? *(const short8v*)(Wrow + kt + 24) : zz;
        *(short8v*)&As[ml * LDK5 + kl]      = a0;
        *(short8v*)&As[ml * LDK5 + kl + 8]  = a1;
        *(short8v*)&As[ml * LDK5 + kl + 16] = a2;
        *(short8v*)&As[ml * LDK5 + kl + 24] = a3;
        *(short8v*)&Bs[ml * LDK5 + kl]      = b0;
        *(short8v*)&Bs[ml * LDK5 + kl + 8]  = b1;
        *(short8v*)&Bs[ml * LDK5 + kl + 16] = b2;
        *(short8v*)&Bs[ml * LDK5 + kl + 24] = b3;
        __syncthreads();

#pragma unroll
        for (int kh = 0; kh < 2; ++kh) {
            short8v af[4], bf[4];
#pragma unroll
            for (int i = 0; i < 4; ++i)
                af[i] = *(const short8v*)&As[(wr * 64 + i * 16 + rr) * LDK5 + kh * 32 + ko * 8];
#pragma unroll
            for (int j = 0; j < 4; ++j)
                bf[j] = *(const short8v*)&Bs[(wc * 64 + j * 16 + rr) * LDK5 + kh * 32 + ko * 8];
#pragma unroll
            for (int i = 0; i < 4; ++i)
#pragma unroll
                for (int j = 0; j < 4; ++j)
                    acc[i][j] = __builtin_amdgcn_mfma_f32_16x16x32_bf16(af[i], bf[j], acc[i][j], 0, 0, 0);
        }
        __syncthreads();
    }

    int cr4 = (lane >> 4) * 4;
    float bov[4];
#pragma unroll
    for (int j = 0; j < 4; ++j) {
        int v = n0 + wc * 64 + j * 16 + rr;
        bov[j] = (v < V_) ? bo[v] : 0.f;
    }
#pragma unroll
    for (int i = 0; i < 4; ++i) {
#pragma unroll
        for (int j = 0; j < 4; ++j) {
            int v = n0 + wc * 64 + j * 16 + rr;
            if (v < V_) {
#pragma unroll
                for (int r = 0; r < 4; ++r) {
                    int m = m0 + wr * 64 + i * 16 + cr4 + r;
                    float x = acc[i][j][r] + bov[j];
                    pOut[(size_t)m * V_ + v] = 1.0f / (1.0f + expf(-x));
                }
            }
        }
    }
}

// ---------------------------------------------------------------------------
// K7a v2: per-wave top-32 via lazy-top-2 tournament. Candidates: 8x32=256/row.
// ---------------------------------------------------------------------------
__global__ __launch_bounds__(512) void k7a_cand(const float* __restrict__ pOut,
                                                float* __restrict__ candV,
                                                int* __restrict__ candI) {
    int row = blockIdx.x;
    int t = threadIdx.x;
    int wv = t >> 6;          // chunk 0..7 (2500 cols each)
    int lane = t & 63;
    const float* rowp = pOut + (size_t)row * V_ + wv * 2500;

    float rv[40];
#pragma unroll
    for (int q4 = 0; q4 < 10; ++q4) {
        int base = q4 * 256 + lane * 4;
        float4 v4 = *(const float4*)(rowp + base);   // tails stay inside d_out; masked below
        float vv[4] = {v4.x, v4.y, v4.z, v4.w};
#pragma unroll
        for (int c = 0; c < 4; ++c) {
            int li = base + c;
            int col = wv * 2500 + li;
            bool ok = (li < 2500) && (col >= 3);
            rv[q4 * 4 + c] = ok ? vv[c] : NEG7;
        }
    }
    float m1 = rv[0]; int s1 = 0;
#pragma unroll
    for (int q = 1; q < 40; ++q)
        if (rv[q] > m1) { m1 = rv[q]; s1 = q; }
    float m2 = NEG7; int s2 = 0;
#pragma unroll
    for (int q = 0; q < 40; ++q)
        if (q != s1 && rv[q] > m2) { m2 = rv[q]; s2 = q; }
    bool dirty = false;
    ull_ used = 0;
    int myidx = wv * 2500 + (s1 >> 2) * 256 + lane * 4 + (s1 & 3);

    float keepv = NEG7; int keepi = 0;
#pragma unroll 1
    for (int r = 0; r < 32; ++r) {
        float bv = m1; int bi = myidx;
#pragma unroll
        for (int m = 1; m < 64; m <<= 1) {
            float ov = __shfl_xor(bv, m);
            int   oi = __shfl_xor(bi, m);
            if (ov > bv || (ov == bv && oi < bi)) { bv = ov; bi = oi; }
        }
        if (lane == r) { keepv = bv; keepi = bi; }
        if (myidx == bi) {           // this lane won (idx unique -> exactly one)
            used |= (1ull << s1);
            if (!dirty) {
                m1 = m2; s1 = s2; dirty = true;
            } else {
                m1 = NEG7; s1 = 0;
#pragma unroll
                for (int q = 0; q < 40; ++q) {
                    float v = ((used >> q) & 1ull) ? NEG7 : rv[q];
                    if (v > m1) { m1 = v; s1 = q; }
                }
                m2 = NEG7; s2 = 0;
#pragma unroll
                for (int q = 0; q < 40; ++q) {
                    float v = (((used >> q) & 1ull) || q == s1) ? NEG7 : rv[q];
                    if (v > m2) { m2 = v; s2 = q; }
                }
                dirty = false;
            }
            myidx = wv * 2500 + (s1 >> 2) * 256 + lane * 4 + (s1 & 3);
        }
    }
    if (lane < 32) {
        size_t o = ((size_t)row * 8 + wv) * 32 + lane;
        candV[o] = keepv;
        candI[o] = keepi;
    }
}

// ---------------------------------------------------------------------------
// K7b: merge 256 candidates -> global top-64 (stable); f64 rescore; final
//     top-30 by (rescored desc, idx asc). Also computes m_output (fused k6).
// ---------------------------------------------------------------------------
__global__ __launch_bounds__(256) void k7b_final(const float* __restrict__ candV,
                                                 const int* __restrict__ candI,
                                                 const float* __restrict__ outs,
                                                 const float* __restrict__ W,
                                                 const float* __restrict__ bo,
                                                 float* __restrict__ mOut,
                                                 float* __restrict__ sOut) {
    __shared__ float selv[64];
    __shared__ int   seli[64];
    __shared__ float resv[64];
    __shared__ float redm[4];
    __shared__ __align__(16) float orow[H_];

    int row = blockIdx.x;
    int t = threadIdx.x;
    int lane = t & 63, wid = t >> 6;

    if (wid != 0) {
        for (int i = t - 64; i < H_; i += 192)
            orow[i] = outs[(size_t)row * H_ + i];
    } else {
        float cv[4]; int ci[4];
#pragma unroll
        for (int q = 0; q < 4; ++q) {
            size_t o = (size_t)row * 256 + q * 64 + lane;
            cv[q] = candV[o];
            ci[q] = candI[o];
        }
        float lv = cv[0]; int lix = ci[0]; int ls = 0;
#pragma unroll
        for (int q = 1; q < 4; ++q)
            if (cv[q] > lv || (cv[q] == lv && ci[q] < lix)) { lv = cv[q]; lix = ci[q]; ls = q; }

#pragma unroll 1
        for (int r = 0; r < 64; ++r) {
            float bv = lv; int bi = lix;
#pragma unroll
            for (int m = 1; m < 64; m <<= 1) {
                float ov = __shfl_xor(bv, m);
                int   oi = __shfl_xor(bi, m);
                if (ov > bv || (ov == bv && oi < bi)) { bv = ov; bi = oi; }
            }
            if (lane == r) { selv[r] = bv; seli[r] = bi; }
            if (lix == bi) {
#pragma unroll
                for (int q = 0; q < 4; ++q) cv[q] = (ls == q) ? NEG7 : cv[q];
                lv = cv[0]; lix = ci[0]; ls = 0;
#pragma unroll
                for (int q = 1; q < 4; ++q)
                    if (cv[q] > lv || (cv[q] == lv && ci[q] < lix)) { lv = cv[q]; lix = ci[q]; ls = q; }
            }
        }
    }
    __syncthreads();

    {
        float ms = fabsf(orow[t]) + fabsf(orow[t + 256]);
#pragma unroll
        for (int m = 1; m < 64; m <<= 1) ms += __shfl_xor(ms, m);
        if (lane == 0) redm[wid] = ms;
    }

    {
        int c = t >> 2, q = t & 3;
        int gidx = seli[c];
        const float4* w4 = (const float4*)(W + (size_t)gidx * H_);
        const float4* o4 = (const float4*)orow;
        double acc = 0.0;
#pragma unroll 8
        for (int i2 = 0; i2 < 32; ++i2) {
            float4 wv4 = w4[i2 * 4 + q];
            float4 ov4 = o4[i2 * 4 + q];
            acc += (double)wv4.x * (double)ov4.x + (double)wv4.y * (double)ov4.y
                 + (double)wv4.z * (double)ov4.z + (double)wv4.w * (double)ov4.w;
        }
        acc += __shfl_xor(acc, 1);
        acc += __shfl_xor(acc, 2);
        if (q == 0) resv[c] = (float)(acc + (double)bo[gidx]);
    }
    __syncthreads();

    if (t == 0)
        mOut[row] = (redm[0] + redm[1] + redm[2] + redm[3] > 0.f) ? 1.f : 0.f;

    if (t < 64) {
        float v = resv[t];
        int idx = seli[t];
#pragma unroll 1
        for (int r = 0; r < MV_; ++r) {
            float bv = v; int bi = idx;
#pragma unroll
            for (int m = 1; m < 64; m <<= 1) {
                float ov = __shfl_xor(bv, m);
                int   oi = __shfl_xor(bi, m);
                if (ov > bv || (ov == bv && oi < bi)) { bv = ov; bi = oi; }
            }
            if (t == 0)
                sOut[(size_t)row * MV_ + r] = (bv <= 0.0f) ? 0.0f : (float)bi;
            if (idx == bi) v = NEG7;
        }
    }
}

// ---------------------------------------------------------------------------
extern "C" void kernel_launch(void* const* d_in, const int* in_sizes, int n_in,
                              void* d_out, int out_size, void* d_ws, size_t ws_size,
                              hipStream_t stream) {
    const float* z      = (const float*)d_in[0];
    const int*   seq    = (const int*)d_in[1];
    const int*   length = (const int*)d_in[2];
    const float* Ew     = (const float*)d_in[3];
    const float* W_l2h  = (const float*)d_in[4];
    const float* b_l2h  = (const float*)d_in[5];
    const float* W_ih   = (const float*)d_in[6];
    const float* W_hh   = (const float*)d_in[7];
    const float* b_ih   = (const float*)d_in[8];
    const float* b_hh   = (const float*)d_in[9];
    const float* W_out  = (const float*)d_in[10];
    const float* b_out  = (const float*)d_in[11];

    float* out = (float*)d_out;

    double* emb_d = (double*)d_ws;               // 2048*256 f64 (A16 overlay after k4)
    double* gi_d  = emb_d + 524288;              // 2048*1536 f64 (W16 overlay after k4)
    double* hglob = gi_d + 3145728;              // 2 x 16384 f64 (parity h, grouped packing)
    float*  outs  = (float*)(hglob + 32768);     // 2048*512 f32
    int*    flags = (int*)(outs + 1048576);      // NB4*FPAD ints
    float*  candV = (float*)(flags + NB4 * FPAD);        // 2048*256 f32
    int*    candI = (int*)(candV + (size_t)BS_ * 256);   // 2048*256 i32
    short*  A16   = (short*)emb_d;               // 2048*512 bf16 (emb dead after k4)
    short*  W16   = (short*)gi_d;                // 20000*512 bf16 (gi dead after k4)

    float* pOut = out;                           // 2048*20000
    float* sOut = out + (size_t)BS_ * V_;        // 2048*30
    float* mOut = sOut + (size_t)BS_ * MV_;      // 2048

    k12<<<BS_ + 65, 256, 0, stream>>>(seq, Ew, z, W_l2h, b_l2h, emb_d, hglob, flags);
    k3_gi<<<dim3(24, 32), 256, 0, stream>>>(emb_d, W_ih, b_ih, gi_d);
    k4_gru<<<NB4, 256, 0, stream>>>(gi_d, W_hh, b_hh, length, hglob, outs, flags);
    k_prep2<<<5512, 256, 0, stream>>>(W_out, outs, W16, A16);
    k5_mfma<<<2512, 256, 0, stream>>>(A16, W16, b_out, pOut);
    k7a_cand<<<BS_, 512, 0, stream>>>(pOut, candV, candI);
    k7b_final<<<BS_, 256, 0, stream>>>(candV, candI, outs, W_out, b_out, mOut, sOut);
}

// Round 3
// 913.868 us; speedup vs baseline: 1.0881x; 1.0053x over previous
//
#include <hip/hip_runtime.h>
#include <hip/hip_bf16.h>
#include <math.h>

// Problem constants
#define B_ 32
#define S_ 64
#define MV_ 30
#define V_ 20000
#define E_ 256
#define H_ 512
#define L_ 128
#define H3_ 1536
#define BS_ 2048   // B*S
#define NB4 256    // k4 grid blocks (persistent, co-resident; 8 groups x 32)
#define FPAD 32    // flag padding (ints) -> one flag per 128B line
#define NEG7 -3.0e38f

typedef __attribute__((ext_vector_type(8))) short short8v;  // 8 bf16 (4 VGPRs)
typedef __attribute__((ext_vector_type(4))) float f32x4;
typedef unsigned long long ull_;

// ---------------------------------------------------------------------------
// K12: blocks [0,2048): k1 multi-hot embed body (verbatim);
//      blocks [2048,2112): k2 h0 body (grouped packing for k4);
//      block 2112: zero-init k4 flags.
// h0 layout: hglob[(b>>2)*2048 + j*4 + (b&3)]  (group-major, unit, batch-in-group)
// ---------------------------------------------------------------------------
__global__ __launch_bounds__(256) void k12(const int* __restrict__ seq,
                                           const float* __restrict__ Ew,
                                           const float* __restrict__ z,
                                           const float* __restrict__ Wl,
                                           const float* __restrict__ bl,
                                           double* __restrict__ emb,
                                           double* __restrict__ hglob,
                                           int* __restrict__ flags) {
    __shared__ int sidx[MV_];
    int bid = blockIdx.x;
    int t = threadIdx.x;
    if (bid < BS_) {
        int row = bid;
        if (t < MV_) sidx[t] = seq[row * MV_ + t];
        __syncthreads();
        double acc = 0.0;
        for (int i = 0; i < MV_; ++i) {
            int id = sidx[i];
            if (id == 0) continue;
            bool dup = false;
            for (int q = 0; q < i; ++q) dup = dup || (sidx[q] == id);
            if (!dup) acc += (double)Ew[(size_t)id * E_ + t];
        }
        emb[(size_t)row * E_ + t] = tanh(acc);
    } else if (bid < BS_ + 64) {
        int o = (bid - BS_) * 256 + t;   // < 16384
        int b = o >> 9;
        int j = o & 511;
        const float4* zr = (const float4*)(z + (size_t)b * L_);
        const float4* wr = (const float4*)(Wl + (size_t)j * L_);
        double acc = (double)bl[j];
#pragma unroll
        for (int k = 0; k < L_ / 4; ++k) {
            float4 a = zr[k];
            float4 w = wr[k];
            acc += (double)a.x * (double)w.x + (double)a.y * (double)w.y
                 + (double)a.z * (double)w.z + (double)a.w * (double)w.w;
        }
        hglob[(size_t)(b >> 2) * 2048 + j * 4 + (b & 3)] = acc;
    } else {
        for (int i = t; i < NB4 * FPAD; i += 256) flags[i] = 0;
    }
}

// ---------------------------------------------------------------------------
// K3: Gi = emb @ W_ih^T + b_ih  (2048x1536, K=256), f64. 64x64 tile, 4x4/thread.
//     Output PACKED for k4: gi_p[(((s*512 + unit)*3 + gate)*32 + b)]
// ---------------------------------------------------------------------------
__global__ __launch_bounds__(256) void k3_gi(const double* __restrict__ A,
                                             const float* __restrict__ Bm,
                                             const float* __restrict__ bih,
                                             double* __restrict__ gi) {
    __shared__ double As[16][66];
    __shared__ double Bs[16][66];
    int t = threadIdx.x;
    int n0 = blockIdx.x * 64;   // 24
    int m0 = blockIdx.y * 64;   // 32
    int tx = t & 15, ty = t >> 4;
    int ml = t >> 2;
    int kl = (t & 3) * 4;
    double acc[4][4];
#pragma unroll
    for (int i = 0; i < 4; ++i)
#pragma unroll
        for (int j = 0; j < 4; ++j) acc[i][j] = 0.0;

    for (int kt = 0; kt < 256; kt += 16) {
        double4 av = *(const double4*)(A + (size_t)(m0 + ml) * 256 + kt + kl);
        float4 bv = *(const float4*)(Bm + (size_t)(n0 + ml) * 256 + kt + kl);
        As[kl + 0][ml] = av.x; As[kl + 1][ml] = av.y; As[kl + 2][ml] = av.z; As[kl + 3][ml] = av.w;
        Bs[kl + 0][ml] = (double)bv.x; Bs[kl + 1][ml] = (double)bv.y;
        Bs[kl + 2][ml] = (double)bv.z; Bs[kl + 3][ml] = (double)bv.w;
        __syncthreads();
#pragma unroll
        for (int kk = 0; kk < 16; ++kk) {
            double2 a01 = *(const double2*)&As[kk][ty * 4];
            double2 a23 = *(const double2*)&As[kk][ty * 4 + 2];
            double2 b01 = *(const double2*)&Bs[kk][tx * 4];
            double2 b23 = *(const double2*)&Bs[kk][tx * 4 + 2];
            double am[4] = {a01.x, a01.y, a23.x, a23.y};
            double bn[4] = {b01.x, b01.y, b23.x, b23.y};
#pragma unroll
            for (int i = 0; i < 4; ++i)
#pragma unroll
                for (int j = 0; j < 4; ++j) acc[i][j] += am[i] * bn[j];
        }
        __syncthreads();
    }
#pragma unroll
    for (int i = 0; i < 4; ++i) {
        int m = m0 + ty * 4 + i;
        int bb = m >> 6, ss = m & 63;
#pragma unroll
        for (int j = 0; j < 4; ++j) {
            int n = n0 + tx * 4 + j;
            int g = n >> 9, u = n & 511;
            gi[(((size_t)(ss * 512 + u)) * 3 + g) * 32 + bb] = acc[i][j] + (double)bih[n];
        }
    }
}

// ---------------------------------------------------------------------------
// K4 (round-12): persistent cooperative GRU, PER-WAVE dataflow sync.
//   256 blocks x 256 thr = 1 block/CU (LDS-forced). Group g=bid&7 owns batches
//   4g..4g+3; block beta=bid>>3 owns units beta*16..+16 (W_hh f32 in LDS).
//   NEW vs round-11: wave wv consumes only h-slice k in [128wv,128wv+128),
//   produced by 8 blocks (beta_p in [8wv,8wv+8)). Each wave polls ONLY those
//   8 flags, restages ONLY its 4KB slice, then runs its matvec immediately —
//   no second barrier. ONE __syncthreads per step (S1: partials ready).
//   part[] is parity double-buffered (next-step writers vs wave0 reader).
//   Safety: wave0 reads hv before publishing; slice-owner wave can't
//   overwrite hl[hvidx] until own block's flag (in its 8-set) advances.
//   Parity double-buffered hglob tolerates the <=1-step inter-block skew
//   (block-level S1 still couples all 4 waves -> publish s+1 needs all 32
//   source flags >= s transitively).
// ---------------------------------------------------------------------------
#define WROW 580   // f32 row stride for wlds (512 + 64 shift pad + 4)
__global__ __launch_bounds__(256, 1) void k4_gru(const double* __restrict__ gi,
                                                 const float* __restrict__ whh,
                                                 const float* __restrict__ bhh,
                                                 const int* __restrict__ length,
                                                 double* __restrict__ hglob,
                                                 float* __restrict__ outs,
                                                 int* __restrict__ flags) {
    __shared__ float  wl[48 * WROW];          // ~108.8 KB
    __shared__ double hl[2112];               // group h: idx = e + (e>>7)*4
    __shared__ double part[2][4][16][3][4];   // [parity][wave][ul][gate][batch]

    int t = threadIdx.x;
    int wv = t >> 6;
    int lane = t & 63;
    int bid = blockIdx.x;
    int g = bid & 7;          // group
    int beta = bid >> 3;      // block-in-group 0..31

    // ---- stage W_hh slice (16 units x 3 gates x 512), injective bank-shift ----
    for (int i = t; i < 6144; i += 256) {
        int r  = i >> 7;            // 0..47  (= ul*3 + gate)
        int c4 = i & 127;
        int uu = r / 3, gg = r - uu * 3;
        int row = (gg << 9) + beta * 16 + uu;       // W_hh row (gate*512 + unit)
        float4 v = *(const float4*)&whh[(size_t)row * 512 + c4 * 4];
        int k = c4 * 4;
        *(float4*)&wl[r * WROW + k + ((k >> 5) << 2)] = v;
    }
    // ---- initial h (parity 0), group-local 16KB ----
    {
        const double* hg0 = hglob + (size_t)g * 2048;
#pragma unroll
        for (int j = 0; j < 8; ++j) {
            int e = t + j * 256;
            hl[e + ((e >> 7) << 2)] = hg0[e];
        }
    }
    __syncthreads();

    // wave0 per-lane elementwise state: lane = (u2 0..15, b2 0..3)
    int u2 = lane >> 2, b2 = lane & 3;
    int u_g = beta * 16 + u2;      // global unit
    int b_g = g * 4 + b2;          // global batch
    double gr = 0.0, gz = 0.0, gn = 0.0, bhr_ = 0.0, bhz_ = 0.0, bhn_ = 0.0;
    int len = 0;
    int hvidx = u_g * 4 + b2 + ((u_g >> 5) << 2);
    if (wv == 0) {
        bhr_ = (double)bhh[u_g];
        bhz_ = (double)bhh[u_g + 512];
        bhn_ = (double)bhh[u_g + 1024];
        len = length[b_g];
        size_t gb = ((size_t)u_g * 3) * 32 + b_g;
        gr = gi[gb]; gz = gi[gb + 32]; gn = gi[gb + 64];
    }

    // matvec lane mapping: (ul, ks); wave wv covers k in [wv*128, wv*128+128)
    int ul = lane >> 2, ks = lane & 3;
    const float*  wr0 = &wl[(ul * 3 + 0) * WROW + wv * 128 + ks * 32 + ((wv * 4 + ks) << 2)];
    const float*  wr1 = wr0 + WROW;
    const float*  wr2 = wr0 + 2 * WROW;
    const double* hr  = &hl[(wv * 128 + ks * 32) * 4 + ((wv * 4 + ks) << 2)];
    // wave wv's h-slice is produced by blocks beta_p in [8wv, 8wv+8): 8 flags
    int srcflag = (g * 32 + wv * 8 + (lane & 7)) * FPAD;

    for (int s = 0; s < S_; ++s) {
        int par = s & 1;
        double a0[4] = {0, 0, 0, 0}, a1[4] = {0, 0, 0, 0}, a2[4] = {0, 0, 0, 0};
#pragma unroll
        for (int c = 0; c < 8; ++c) {
            float4 w0 = *(const float4*)(wr0 + c * 4);
            float4 w1 = *(const float4*)(wr1 + c * 4);
            float4 w2 = *(const float4*)(wr2 + c * 4);
            float f0[4] = {w0.x, w0.y, w0.z, w0.w};
            float f1[4] = {w1.x, w1.y, w1.z, w1.w};
            float f2[4] = {w2.x, w2.y, w2.z, w2.w};
#pragma unroll
            for (int j = 0; j < 4; ++j) {
                const double* hp = hr + (c * 4 + j) * 4;
                double2 hA = *(const double2*)hp;
                double2 hB = *(const double2*)(hp + 2);
                double d0 = (double)f0[j], d1 = (double)f1[j], d2 = (double)f2[j];
                a0[0] += hA.x * d0; a0[1] += hA.y * d0; a0[2] += hB.x * d0; a0[3] += hB.y * d0;
                a1[0] += hA.x * d1; a1[1] += hA.y * d1; a1[2] += hB.x * d1; a1[3] += hB.y * d1;
                a2[0] += hA.x * d2; a2[1] += hA.y * d2; a2[2] += hB.x * d2; a2[3] += hB.y * d2;
            }
        }
        // reduce over ks (lanes xor 1, 2)
#pragma unroll
        for (int b = 0; b < 4; ++b) {
            a0[b] += __shfl_xor(a0[b], 1); a0[b] += __shfl_xor(a0[b], 2);
            a1[b] += __shfl_xor(a1[b], 1); a1[b] += __shfl_xor(a1[b], 2);
            a2[b] += __shfl_xor(a2[b], 1); a2[b] += __shfl_xor(a2[b], 2);
        }
        if (ks == 0) {
#pragma unroll
            for (int b = 0; b < 4; ++b) {
                part[par][wv][ul][0][b] = a0[b];
                part[par][wv][ul][1][b] = a1[b];
                part[par][wv][ul][2][b] = a2[b];
            }
        }
        __syncthreads();   // S1 (only barrier per step): partials visible

        if (wv == 0) {
            double hv = hl[hvidx];   // read BEFORE publish; overwriter waits on our flag
            double s0 = part[par][0][u2][0][b2] + part[par][1][u2][0][b2] + part[par][2][u2][0][b2] + part[par][3][u2][0][b2];
            double s1 = part[par][0][u2][1][b2] + part[par][1][u2][1][b2] + part[par][2][u2][1][b2] + part[par][3][u2][1][b2];
            double s2 = part[par][0][u2][2][b2] + part[par][1][u2][2][b2] + part[par][2][u2][2][b2] + part[par][3][u2][2][b2];
            double r  = 1.0 / (1.0 + exp(-(gr + s0 + bhr_)));
            double zt = 1.0 / (1.0 + exp(-(gz + s1 + bhz_)));
            double n  = tanh(gn + r * (s2 + bhn_));
            double hn_ = (1.0 - zt) * n + zt * hv;
            outs[(size_t)(b_g * 64 + s) * H_ + u_g] = (s < len) ? (float)hn_ : 0.0f;
            if (s < S_ - 1) {
                double* hdst = hglob + ((size_t)((s + 1) & 1)) * 16384 + (size_t)g * 2048;
                // (beta*16+u2)*4 + b2 == beta*64 + lane -> fully coalesced 512B store
                __hip_atomic_store((ull_*)&hdst[beta * 64 + lane],
                                   __builtin_bit_cast(ull_, hn_),
                                   __ATOMIC_RELAXED, __HIP_MEMORY_SCOPE_AGENT);
                if (lane == 0)
                    __hip_atomic_store(&flags[(g * 32 + beta) * FPAD], s + 1,
                                       __ATOMIC_RELEASE, __HIP_MEMORY_SCOPE_AGENT);
                // gi prefetch for s+1: issued after the release store so it
                // doesn't delay the flag; overlaps the poll below.
                size_t gb = ((size_t)((s + 1) * 512 + u_g) * 3) * 32 + b_g;
                gr = gi[gb]; gz = gi[gb + 32]; gn = gi[gb + 64];
            }
        }
        if (s == S_ - 1) break;

        // ---- per-wave poll: only this wave's 8 source-block flags ----
        {
            bool seen = (lane >= 8);
            while (!__all(seen)) {
                if (!seen)
                    seen = __hip_atomic_load(&flags[srcflag], __ATOMIC_RELAXED,
                                             __HIP_MEMORY_SCOPE_AGENT) >= s + 1;
                if (!__all(seen)) __builtin_amdgcn_s_sleep(1);
            }
        }
        asm volatile("" ::: "memory");
        // ---- per-wave restage of OWN 4KB slice; straight into next matvec ----
        {
            const ull_* hgu =
                (const ull_*)(hglob + ((size_t)((s + 1) & 1)) * 16384 + (size_t)g * 2048);
            ull_ tmp[8];
#pragma unroll
            for (int j = 0; j < 8; ++j)
                tmp[j] = __hip_atomic_load(&hgu[wv * 512 + j * 64 + lane],
                                           __ATOMIC_RELAXED, __HIP_MEMORY_SCOPE_AGENT);
            ull_* hlu = (ull_*)hl;
#pragma unroll
            for (int j = 0; j < 8; ++j) {
                int e = wv * 512 + j * 64 + lane;
                hlu[e + ((e >> 7) << 2)] = tmp[j];
            }
        }
        // no second barrier: each wave reads only its own slice in the matvec;
        // wave0's hv read is protected by the publish/poll dependency.
    }
}

// ---------------------------------------------------------------------------
// bf16 helpers + fused prep kernel: blocks [0,5000) convert W_out -> W16,
// blocks [5000,5512) convert outs -> A16.
// ---------------------------------------------------------------------------
__device__ __forceinline__ unsigned short f2b_(float x) {
    unsigned u = __builtin_bit_cast(unsigned, x);
    return (unsigned short)((u + 0x7FFFu + ((u >> 16) & 1u)) >> 16);   // RNE
}
__device__ __forceinline__ short8v pack8_(float4 a, float4 b) {
    short8v r;
    r[0] = (short)f2b_(a.x); r[1] = (short)f2b_(a.y);
    r[2] = (short)f2b_(a.z); r[3] = (short)f2b_(a.w);
    r[4] = (short)f2b_(b.x); r[5] = (short)f2b_(b.y);
    r[6] = (short)f2b_(b.z); r[7] = (short)f2b_(b.w);
    return r;
}
__global__ __launch_bounds__(256) void k_prep2(const float* __restrict__ Wsrc,
                                               const float* __restrict__ Asrc,
                                               short* __restrict__ W16,
                                               short* __restrict__ A16) {
    int bid = blockIdx.x, t = threadIdx.x;
    if (bid < 5000) {
        int i = bid * 256 + t;               // < 1,280,000
        float4 a = *(const float4*)&Wsrc[(size_t)i * 8];
        float4 b = *(const float4*)&Wsrc[(size_t)i * 8 + 4];
        *(short8v*)&W16[(size_t)i * 8] = pack8_(a, b);
    } else {
        int i = (bid - 5000) * 256 + t;      // < 131072
        float4 a = *(const float4*)&Asrc[(size_t)i * 8];
        float4 b = *(const float4*)&Asrc[(size_t)i * 8 + 4];
        *(short8v*)&A16[(size_t)i * 8] = pack8_(a, b);
    }
}

// ---------------------------------------------------------------------------
// K5: p = sigmoid(outs_bf16 @ W_bf16^T + b_out), bf16 MFMA. BK=64.
//     128x128 tile, 4 waves (2x2 of 64x64), LDS stride 72.
// ---------------------------------------------------------------------------
#define LDK5 72
__global__ __launch_bounds__(256, 2) void k5_mfma(const short* __restrict__ A16,  // 2048x512 bf16
                                                  const short* __restrict__ W16,  // 20000x512 bf16
                                                  const float* __restrict__ bo,
                                                  float* __restrict__ pOut) {
    __shared__ short As[128 * LDK5];   // 18.4KB
    __shared__ short Bs[128 * LDK5];
    int t = threadIdx.x;
    int bid = blockIdx.x;                       // 0..2511
    int swz = (bid & 7) * 314 + (bid >> 3);     // XCD swizzle (bijective, 2512=8*314)
    int m0 = (swz & 15) * 128;
    int n0 = (swz >> 4) * 128;
    int lane = t & 63, wv = t >> 6;
    int wr = wv >> 1, wc = wv & 1;              // wave -> 64x64 quadrant
    int ml = t >> 1;                            // 0..127 (staging row)
    int kl = (t & 1) * 32;                      // 0 or 32 (staging k-offset)

    const short* Arow = A16 + (size_t)(m0 + ml) * H_ + kl;
    int vrow = n0 + ml;
    bool vok = vrow < V_;
    const short* Wrow = W16 + (size_t)(vok ? vrow : 0) * H_ + kl;
    short8v zz = (short8v){0, 0, 0, 0, 0, 0, 0, 0};

    f32x4 acc[4][4];
#pragma unroll
    for (int i = 0; i < 4; ++i)
#pragma unroll
        for (int j = 0; j < 4; ++j) acc[i][j] = (f32x4){0.f, 0.f, 0.f, 0.f};

    int ko = lane >> 4;       // 0..3 (k-group of 8)
    int rr = lane & 15;       // fragment row/col

    for (int kt = 0; kt < H_; kt += 64) {
        short8v a0 = *(const short8v*)(Arow + kt);
        short8v a1 = *(const short8v*)(Arow + kt + 8);
        short8v a2 = *(const short8v*)(Arow + kt + 16);
        short8v a3 = *(const short8v*)(Arow + kt + 24);
        short8v b0 = vok ? *(const short8v*)(Wrow + kt) : zz;
        short8v b1 = vok ? *(const short8v*)(Wrow + kt + 8) : zz;
        short8v b2 = vok ? *(const short8v*)(Wrow + kt + 16) : zz;
        short8v b3 = vok ? *(const short8v*)(Wrow + kt + 24) : zz;
        *(short8v*)&As[ml * LDK5 + kl]      = a0;
        *(short8v*)&As[ml * LDK5 + kl + 8]  = a1;
        *(short8v*)&As[ml * LDK5 + kl + 16] = a2;
        *(short8v*)&As[ml * LDK5 + kl + 24] = a3;
        *(short8v*)&Bs[ml * LDK5 + kl]      = b0;
        *(short8v*)&Bs[ml * LDK5 + kl + 8]  = b1;
        *(short8v*)&Bs[ml * LDK5 + kl + 16] = b2;
        *(short8v*)&Bs[ml * LDK5 + kl + 24] = b3;
        __syncthreads();

#pragma unroll
        for (int kh = 0; kh < 2; ++kh) {
            short8v af[4], bf[4];
#pragma unroll
            for (int i = 0; i < 4; ++i)
                af[i] = *(const short8v*)&As[(wr * 64 + i * 16 + rr) * LDK5 + kh * 32 + ko * 8];
#pragma unroll
            for (int j = 0; j < 4; ++j)
                bf[j] = *(const short8v*)&Bs[(wc * 64 + j * 16 + rr) * LDK5 + kh * 32 + ko * 8];
#pragma unroll
            for (int i = 0; i < 4; ++i)
#pragma unroll
                for (int j = 0; j < 4; ++j)
                    acc[i][j] = __builtin_amdgcn_mfma_f32_16x16x32_bf16(af[i], bf[j], acc[i][j], 0, 0, 0);
        }
        __syncthreads();
    }

    int cr4 = (lane >> 4) * 4;
    float bov[4];
#pragma unroll
    for (int j = 0; j < 4; ++j) {
        int v = n0 + wc * 64 + j * 16 + rr;
        bov[j] = (v < V_) ? bo[v] : 0.f;
    }
#pragma unroll
    for (int i = 0; i < 4; ++i) {
#pragma unroll
        for (int j = 0; j < 4; ++j) {
            int v = n0 + wc * 64 + j * 16 + rr;
            if (v < V_) {
#pragma unroll
                for (int r = 0; r < 4; ++r) {
                    int m = m0 + wr * 64 + i * 16 + cr4 + r;
                    float x = acc[i][j][r] + bov[j];
                    pOut[(size_t)m * V_ + v] = 1.0f / (1.0f + expf(-x));
                }
            }
        }
    }
}

// ---------------------------------------------------------------------------
// K7a v2: per-wave top-32 via lazy-top-2 tournament. Candidates: 8x32=256/row.
// ---------------------------------------------------------------------------
__global__ __launch_bounds__(512) void k7a_cand(const float* __restrict__ pOut,
                                                float* __restrict__ candV,
                                                int* __restrict__ candI) {
    int row = blockIdx.x;
    int t = threadIdx.x;
    int wv = t >> 6;          // chunk 0..7 (2500 cols each)
    int lane = t & 63;
    const float* rowp = pOut + (size_t)row * V_ + wv * 2500;

    float rv[40];
#pragma unroll
    for (int q4 = 0; q4 < 10; ++q4) {
        int base = q4 * 256 + lane * 4;
        float4 v4 = *(const float4*)(rowp + base);   // tails stay inside d_out; masked below
        float vv[4] = {v4.x, v4.y, v4.z, v4.w};
#pragma unroll
        for (int c = 0; c < 4; ++c) {
            int li = base + c;
            int col = wv * 2500 + li;
            bool ok = (li < 2500) && (col >= 3);
            rv[q4 * 4 + c] = ok ? vv[c] : NEG7;
        }
    }
    float m1 = rv[0]; int s1 = 0;
#pragma unroll
    for (int q = 1; q < 40; ++q)
        if (rv[q] > m1) { m1 = rv[q]; s1 = q; }
    float m2 = NEG7; int s2 = 0;
#pragma unroll
    for (int q = 0; q < 40; ++q)
        if (q != s1 && rv[q] > m2) { m2 = rv[q]; s2 = q; }
    bool dirty = false;
    ull_ used = 0;
    int myidx = wv * 2500 + (s1 >> 2) * 256 + lane * 4 + (s1 & 3);

    float keepv = NEG7; int keepi = 0;
#pragma unroll 1
    for (int r = 0; r < 32; ++r) {
        float bv = m1; int bi = myidx;
#pragma unroll
        for (int m = 1; m < 64; m <<= 1) {
            float ov = __shfl_xor(bv, m);
            int   oi = __shfl_xor(bi, m);
            if (ov > bv || (ov == bv && oi < bi)) { bv = ov; bi = oi; }
        }
        if (lane == r) { keepv = bv; keepi = bi; }
        if (myidx == bi) {           // this lane won (idx unique -> exactly one)
            used |= (1ull << s1);
            if (!dirty) {
                m1 = m2; s1 = s2; dirty = true;
            } else {
                m1 = NEG7; s1 = 0;
#pragma unroll
                for (int q = 0; q < 40; ++q) {
                    float v = ((used >> q) & 1ull) ? NEG7 : rv[q];
                    if (v > m1) { m1 = v; s1 = q; }
                }
                m2 = NEG7; s2 = 0;
#pragma unroll
                for (int q = 0; q < 40; ++q) {
                    float v = (((used >> q) & 1ull) || q == s1) ? NEG7 : rv[q];
                    if (v > m2) { m2 = v; s2 = q; }
                }
                dirty = false;
            }
            myidx = wv * 2500 + (s1 >> 2) * 256 + lane * 4 + (s1 & 3);
        }
    }
    if (lane < 32) {
        size_t o = ((size_t)row * 8 + wv) * 32 + lane;
        candV[o] = keepv;
        candI[o] = keepi;
    }
}

// ---------------------------------------------------------------------------
// K7b: merge 256 candidates -> global top-64 (stable); f64 rescore; final
//     top-30 by (rescored desc, idx asc). Also computes m_output (fused k6).
// ---------------------------------------------------------------------------
__global__ __launch_bounds__(256) void k7b_final(const float* __restrict__ candV,
                                                 const int* __restrict__ candI,
                                                 const float* __restrict__ outs,
                                                 const float* __restrict__ W,
                                                 const float* __restrict__ bo,
                                                 float* __restrict__ mOut,
                                                 float* __restrict__ sOut) {
    __shared__ float selv[64];
    __shared__ int   seli[64];
    __shared__ float resv[64];
    __shared__ float redm[4];
    __shared__ __align__(16) float orow[H_];

    int row = blockIdx.x;
    int t = threadIdx.x;
    int lane = t & 63, wid = t >> 6;

    if (wid != 0) {
        for (int i = t - 64; i < H_; i += 192)
            orow[i] = outs[(size_t)row * H_ + i];
    } else {
        float cv[4]; int ci[4];
#pragma unroll
        for (int q = 0; q < 4; ++q) {
            size_t o = (size_t)row * 256 + q * 64 + lane;
            cv[q] = candV[o];
            ci[q] = candI[o];
        }
        float lv = cv[0]; int lix = ci[0]; int ls = 0;
#pragma unroll
        for (int q = 1; q < 4; ++q)
            if (cv[q] > lv || (cv[q] == lv && ci[q] < lix)) { lv = cv[q]; lix = ci[q]; ls = q; }

#pragma unroll 1
        for (int r = 0; r < 64; ++r) {
            float bv = lv; int bi = lix;
#pragma unroll
            for (int m = 1; m < 64; m <<= 1) {
                float ov = __shfl_xor(bv, m);
                int   oi = __shfl_xor(bi, m);
                if (ov > bv || (ov == bv && oi < bi)) { bv = ov; bi = oi; }
            }
            if (lane == r) { selv[r] = bv; seli[r] = bi; }
            if (lix == bi) {
#pragma unroll
                for (int q = 0; q < 4; ++q) cv[q] = (ls == q) ? NEG7 : cv[q];
                lv = cv[0]; lix = ci[0]; ls = 0;
#pragma unroll
                for (int q = 1; q < 4; ++q)
                    if (cv[q] > lv || (cv[q] == lv && ci[q] < lix)) { lv = cv[q]; lix = ci[q]; ls = q; }
            }
        }
    }
    __syncthreads();

    {
        float ms = fabsf(orow[t]) + fabsf(orow[t + 256]);
#pragma unroll
        for (int m = 1; m < 64; m <<= 1) ms += __shfl_xor(ms, m);
        if (lane == 0) redm[wid] = ms;
    }

    {
        int c = t >> 2, q = t & 3;
        int gidx = seli[c];
        const float4* w4 = (const float4*)(W + (size_t)gidx * H_);
        const float4* o4 = (const float4*)orow;
        double acc = 0.0;
#pragma unroll 8
        for (int i2 = 0; i2 < 32; ++i2) {
            float4 wv4 = w4[i2 * 4 + q];
            float4 ov4 = o4[i2 * 4 + q];
            acc += (double)wv4.x * (double)ov4.x + (double)wv4.y * (double)ov4.y
                 + (double)wv4.z * (double)ov4.z + (double)wv4.w * (double)ov4.w;
        }
        acc += __shfl_xor(acc, 1);
        acc += __shfl_xor(acc, 2);
        if (q == 0) resv[c] = (float)(acc + (double)bo[gidx]);
    }
    __syncthreads();

    if (t == 0)
        mOut[row] = (redm[0] + redm[1] + redm[2] + redm[3] > 0.f) ? 1.f : 0.f;

    if (t < 64) {
        float v = resv[t];
        int idx = seli[t];
#pragma unroll 1
        for (int r = 0; r < MV_; ++r) {
            float bv = v; int bi = idx;
#pragma unroll
            for (int m = 1; m < 64; m <<= 1) {
                float ov = __shfl_xor(bv, m);
                int   oi = __shfl_xor(bi, m);
                if (ov > bv || (ov == bv && oi < bi)) { bv = ov; bi = oi; }
            }
            if (t == 0)
                sOut[(size_t)row * MV_ + r] = (bv <= 0.0f) ? 0.0f : (float)bi;
            if (idx == bi) v = NEG7;
        }
    }
}

// ---------------------------------------------------------------------------
extern "C" void kernel_launch(void* const* d_in, const int* in_sizes, int n_in,
                              void* d_out, int out_size, void* d_ws, size_t ws_size,
                              hipStream_t stream) {
    const float* z      = (const float*)d_in[0];
    const int*   seq    = (const int*)d_in[1];
    const int*   length = (const int*)d_in[2];
    const float* Ew     = (const float*)d_in[3];
    const float* W_l2h  = (const float*)d_in[4];
    const float* b_l2h  = (const float*)d_in[5];
    const float* W_ih   = (const float*)d_in[6];
    const float* W_hh   = (const float*)d_in[7];
    const float* b_ih   = (const float*)d_in[8];
    const float* b_hh   = (const float*)d_in[9];
    const float* W_out  = (const float*)d_in[10];
    const float* b_out  = (const float*)d_in[11];

    float* out = (float*)d_out;

    double* emb_d = (double*)d_ws;               // 2048*256 f64 (A16 overlay after k4)
    double* gi_d  = emb_d + 524288;              // 2048*1536 f64 (W16 overlay after k4)
    double* hglob = gi_d + 3145728;              // 2 x 16384 f64 (parity h, grouped packing)
    float*  outs  = (float*)(hglob + 32768);     // 2048*512 f32
    int*    flags = (int*)(outs + 1048576);      // NB4*FPAD ints
    float*  candV = (float*)(flags + NB4 * FPAD);        // 2048*256 f32
    int*    candI = (int*)(candV + (size_t)BS_ * 256);   // 2048*256 i32
    short*  A16   = (short*)emb_d;               // 2048*512 bf16 (emb dead after k4)
    short*  W16   = (short*)gi_d;                // 20000*512 bf16 (gi dead after k4)

    float* pOut = out;                           // 2048*20000
    float* sOut = out + (size_t)BS_ * V_;        // 2048*30
    float* mOut = sOut + (size_t)BS_ * MV_;      // 2048

    k12<<<BS_ + 65, 256, 0, stream>>>(seq, Ew, z, W_l2h, b_l2h, emb_d, hglob, flags);
    k3_gi<<<dim3(24, 32), 256, 0, stream>>>(emb_d, W_ih, b_ih, gi_d);
    k4_gru<<<NB4, 256, 0, stream>>>(gi_d, W_hh, b_hh, length, hglob, outs, flags);
    k_prep2<<<5512, 256, 0, stream>>>(W_out, outs, W16, A16);
    k5_mfma<<<2512, 256, 0, stream>>>(A16, W16, b_out, pOut);
    k7a_cand<<<BS_, 512, 0, stream>>>(pOut, candV, candI);
    k7b_final<<<BS_, 256, 0, stream>>>(candV, candI, outs, W_out, b_out, mOut, sOut);
}

// Round 4
// 803.133 us; speedup vs baseline: 1.2382x; 1.1379x over previous
//
#include <hip/hip_runtime.h>
#include <hip/hip_bf16.h>
#include <math.h>

// Problem constants
#define B_ 32
#define S_ 64
#define MV_ 30
#define V_ 20000
#define E_ 256
#define H_ 512
#define L_ 128
#define H3_ 1536
#define BS_ 2048   // B*S
#define NB4 256    // k4 grid blocks (persistent, co-resident; 8 groups x 32)
#define FPAD 32    // flag padding (ints) -> one flag per 128B line
#define NEG7 -3.0e38f

typedef __attribute__((ext_vector_type(8))) short short8v;  // 8 bf16 (4 VGPRs)
typedef __attribute__((ext_vector_type(4))) float f32x4;
typedef unsigned long long ull_;

// ---------------------------------------------------------------------------
// K12: blocks [0,2048): k1 multi-hot embed body (verbatim);
//      blocks [2048,2112): k2 h0 body (grouped packing for k4);
//      block 2112: zero-init k4 flags.
// h0 layout: hglob[(b>>2)*2048 + j*4 + (b&3)]  (group-major, unit, batch-in-group)
// ---------------------------------------------------------------------------
__global__ __launch_bounds__(256) void k12(const int* __restrict__ seq,
                                           const float* __restrict__ Ew,
                                           const float* __restrict__ z,
                                           const float* __restrict__ Wl,
                                           const float* __restrict__ bl,
                                           double* __restrict__ emb,
                                           double* __restrict__ hglob,
                                           int* __restrict__ flags) {
    __shared__ int sidx[MV_];
    int bid = blockIdx.x;
    int t = threadIdx.x;
    if (bid < BS_) {
        int row = bid;
        if (t < MV_) sidx[t] = seq[row * MV_ + t];
        __syncthreads();
        double acc = 0.0;
        for (int i = 0; i < MV_; ++i) {
            int id = sidx[i];
            if (id == 0) continue;
            bool dup = false;
            for (int q = 0; q < i; ++q) dup = dup || (sidx[q] == id);
            if (!dup) acc += (double)Ew[(size_t)id * E_ + t];
        }
        emb[(size_t)row * E_ + t] = tanh(acc);
    } else if (bid < BS_ + 64) {
        int o = (bid - BS_) * 256 + t;   // < 16384
        int b = o >> 9;
        int j = o & 511;
        const float4* zr = (const float4*)(z + (size_t)b * L_);
        const float4* wr = (const float4*)(Wl + (size_t)j * L_);
        double acc = (double)bl[j];
#pragma unroll
        for (int k = 0; k < L_ / 4; ++k) {
            float4 a = zr[k];
            float4 w = wr[k];
            acc += (double)a.x * (double)w.x + (double)a.y * (double)w.y
                 + (double)a.z * (double)w.z + (double)a.w * (double)w.w;
        }
        hglob[(size_t)(b >> 2) * 2048 + j * 4 + (b & 3)] = acc;
    } else {
        for (int i = t; i < NB4 * FPAD; i += 256) flags[i] = 0;
    }
}

// ---------------------------------------------------------------------------
// K3: Gi = emb @ W_ih^T + b_ih  (2048x1536, K=256), f64. 64x64 tile, 4x4/thread.
//     Output PACKED for k4: gi_p[(((s*512 + unit)*3 + gate)*32 + b)]
// ---------------------------------------------------------------------------
__global__ __launch_bounds__(256) void k3_gi(const double* __restrict__ A,
                                             const float* __restrict__ Bm,
                                             const float* __restrict__ bih,
                                             double* __restrict__ gi) {
    __shared__ double As[16][66];
    __shared__ double Bs[16][66];
    int t = threadIdx.x;
    int n0 = blockIdx.x * 64;   // 24
    int m0 = blockIdx.y * 64;   // 32
    int tx = t & 15, ty = t >> 4;
    int ml = t >> 2;
    int kl = (t & 3) * 4;
    double acc[4][4];
#pragma unroll
    for (int i = 0; i < 4; ++i)
#pragma unroll
        for (int j = 0; j < 4; ++j) acc[i][j] = 0.0;

    for (int kt = 0; kt < 256; kt += 16) {
        double4 av = *(const double4*)(A + (size_t)(m0 + ml) * 256 + kt + kl);
        float4 bv = *(const float4*)(Bm + (size_t)(n0 + ml) * 256 + kt + kl);
        As[kl + 0][ml] = av.x; As[kl + 1][ml] = av.y; As[kl + 2][ml] = av.z; As[kl + 3][ml] = av.w;
        Bs[kl + 0][ml] = (double)bv.x; Bs[kl + 1][ml] = (double)bv.y;
        Bs[kl + 2][ml] = (double)bv.z; Bs[kl + 3][ml] = (double)bv.w;
        __syncthreads();
#pragma unroll
        for (int kk = 0; kk < 16; ++kk) {
            double2 a01 = *(const double2*)&As[kk][ty * 4];
            double2 a23 = *(const double2*)&As[kk][ty * 4 + 2];
            double2 b01 = *(const double2*)&Bs[kk][tx * 4];
            double2 b23 = *(const double2*)&Bs[kk][tx * 4 + 2];
            double am[4] = {a01.x, a01.y, a23.x, a23.y};
            double bn[4] = {b01.x, b01.y, b23.x, b23.y};
#pragma unroll
            for (int i = 0; i < 4; ++i)
#pragma unroll
                for (int j = 0; j < 4; ++j) acc[i][j] += am[i] * bn[j];
        }
        __syncthreads();
    }
#pragma unroll
    for (int i = 0; i < 4; ++i) {
        int m = m0 + ty * 4 + i;
        int bb = m >> 6, ss = m & 63;
#pragma unroll
        for (int j = 0; j < 4; ++j) {
            int n = n0 + tx * 4 + j;
            int g = n >> 9, u = n & 511;
            gi[(((size_t)(ss * 512 + u)) * 3 + g) * 32 + bb] = acc[i][j] + (double)bih[n];
        }
    }
}

// ---------------------------------------------------------------------------
// K4 (round-13): persistent cooperative GRU, per-wave dataflow sync (proven
//   round-12 skeleton) + LATENCY-ORIENTED COMPUTE REWORK:
//   * W_hh slice lives in REGISTERS (24 float4/lane, preloaded once from
//     global) — wl LDS staging and 24 of 88 per-step ds_reads deleted.
//   * part[] stride 12 -> 13 doubles (bank stride 26, gcd(26,32)=2):
//     conflict-free partial writes (was 4-way, 1.26e7 conflict cycles).
//   * outs store moved AFTER the release flag store so the release's vmcnt
//     drain covers only the coalesced 512B h-store.
//   * 64KB LDS filler keeps LDS >80KB -> deterministic 1 block/CU placement.
//   Accumulation order is bit-identical to the round-12 passing kernel.
// ---------------------------------------------------------------------------
__global__ __launch_bounds__(256, 1) void k4_gru(const double* __restrict__ gi,
                                                 const float* __restrict__ whh,
                                                 const float* __restrict__ bhh,
                                                 const int* __restrict__ length,
                                                 double* __restrict__ hglob,
                                                 float* __restrict__ outs,
                                                 int* __restrict__ flags) {
    __shared__ double hl[2112];               // group h: idx = e + (e>>7)*4
    __shared__ double part[2][4][16][13];     // [parity][wave][ul][gate*4+b], pad 13
    __shared__ double ldsfill[8192];          // 64KB: force 1 block/CU placement

    int t = threadIdx.x;
    int wv = t >> 6;
    int lane = t & 63;
    int bid = blockIdx.x;
    int g = bid & 7;          // group
    int beta = bid >> 3;      // block-in-group 0..31
    if (bid > 0x00ffffff) ldsfill[t] = 0.0;   // never true; keeps allocation

    // matvec lane mapping: (ul, ks); wave wv covers k in [wv*128, wv*128+128)
    int ul = lane >> 2, ks = lane & 3;

    // ---- W_hh slice into registers: rows (gate*512 + beta*16 + ul),
    //      cols [wv*128 + ks*32, +32) = 8 float4 per gate ----
    const float* wbase = whh + ((size_t)(beta * 16 + ul)) * 512 + wv * 128 + ks * 32;
    float4 w0r[8], w1r[8], w2r[8];
#pragma unroll
    for (int c = 0; c < 8; ++c) {
        w0r[c] = *(const float4*)(wbase + c * 4);
        w1r[c] = *(const float4*)(wbase + 512 * 512 + c * 4);
        w2r[c] = *(const float4*)(wbase + 1024 * 512 + c * 4);
    }

    // ---- initial h (parity 0), group-local 16KB ----
    {
        const double* hg0 = hglob + (size_t)g * 2048;
#pragma unroll
        for (int j = 0; j < 8; ++j) {
            int e = t + j * 256;
            hl[e + ((e >> 7) << 2)] = hg0[e];
        }
    }
    __syncthreads();

    // wave0 per-lane elementwise state: lane = (u2 0..15, b2 0..3)
    int u2 = lane >> 2, b2 = lane & 3;
    int u_g = beta * 16 + u2;      // global unit
    int b_g = g * 4 + b2;          // global batch
    double gr = 0.0, gz = 0.0, gn = 0.0, bhr_ = 0.0, bhz_ = 0.0, bhn_ = 0.0;
    int len = 0;
    int hvidx = u_g * 4 + b2 + ((u_g >> 5) << 2);
    if (wv == 0) {
        bhr_ = (double)bhh[u_g];
        bhz_ = (double)bhh[u_g + 512];
        bhn_ = (double)bhh[u_g + 1024];
        len = length[b_g];
        size_t gb = ((size_t)u_g * 3) * 32 + b_g;
        gr = gi[gb]; gz = gi[gb + 32]; gn = gi[gb + 64];
    }

    const double* hr = &hl[(wv * 128 + ks * 32) * 4 + ((wv * 4 + ks) << 2)];
    // wave wv's h-slice is produced by blocks beta_p in [8wv, 8wv+8): 8 flags
    int srcflag = (g * 32 + wv * 8 + (lane & 7)) * FPAD;

    for (int s = 0; s < S_; ++s) {
        int par = s & 1;
        double a0[4] = {0, 0, 0, 0}, a1[4] = {0, 0, 0, 0}, a2[4] = {0, 0, 0, 0};
#pragma unroll
        for (int c = 0; c < 8; ++c) {
            const double* hp = hr + c * 16;
            double2 hA0 = *(const double2*)(hp + 0),  hB0 = *(const double2*)(hp + 2);
            double2 hA1 = *(const double2*)(hp + 4),  hB1 = *(const double2*)(hp + 6);
            double2 hA2 = *(const double2*)(hp + 8),  hB2 = *(const double2*)(hp + 10);
            double2 hA3 = *(const double2*)(hp + 12), hB3 = *(const double2*)(hp + 14);
            float4 w0 = w0r[c], w1 = w1r[c], w2 = w2r[c];
            // j = 0
            { double d0 = (double)w0.x, d1 = (double)w1.x, d2 = (double)w2.x;
              a0[0] += hA0.x * d0; a0[1] += hA0.y * d0; a0[2] += hB0.x * d0; a0[3] += hB0.y * d0;
              a1[0] += hA0.x * d1; a1[1] += hA0.y * d1; a1[2] += hB0.x * d1; a1[3] += hB0.y * d1;
              a2[0] += hA0.x * d2; a2[1] += hA0.y * d2; a2[2] += hB0.x * d2; a2[3] += hB0.y * d2; }
            // j = 1
            { double d0 = (double)w0.y, d1 = (double)w1.y, d2 = (double)w2.y;
              a0[0] += hA1.x * d0; a0[1] += hA1.y * d0; a0[2] += hB1.x * d0; a0[3] += hB1.y * d0;
              a1[0] += hA1.x * d1; a1[1] += hA1.y * d1; a1[2] += hB1.x * d1; a1[3] += hB1.y * d1;
              a2[0] += hA1.x * d2; a2[1] += hA1.y * d2; a2[2] += hB1.x * d2; a2[3] += hB1.y * d2; }
            // j = 2
            { double d0 = (double)w0.z, d1 = (double)w1.z, d2 = (double)w2.z;
              a0[0] += hA2.x * d0; a0[1] += hA2.y * d0; a0[2] += hB2.x * d0; a0[3] += hB2.y * d0;
              a1[0] += hA2.x * d1; a1[1] += hA2.y * d1; a1[2] += hB2.x * d1; a1[3] += hB2.y * d1;
              a2[0] += hA2.x * d2; a2[1] += hA2.y * d2; a2[2] += hB2.x * d2; a2[3] += hB2.y * d2; }
            // j = 3
            { double d0 = (double)w0.w, d1 = (double)w1.w, d2 = (double)w2.w;
              a0[0] += hA3.x * d0; a0[1] += hA3.y * d0; a0[2] += hB3.x * d0; a0[3] += hB3.y * d0;
              a1[0] += hA3.x * d1; a1[1] += hA3.y * d1; a1[2] += hB3.x * d1; a1[3] += hB3.y * d1;
              a2[0] += hA3.x * d2; a2[1] += hA3.y * d2; a2[2] += hB3.x * d2; a2[3] += hB3.y * d2; }
        }
        // reduce over ks (lanes xor 1, 2)
#pragma unroll
        for (int b = 0; b < 4; ++b) {
            a0[b] += __shfl_xor(a0[b], 1); a0[b] += __shfl_xor(a0[b], 2);
            a1[b] += __shfl_xor(a1[b], 1); a1[b] += __shfl_xor(a1[b], 2);
            a2[b] += __shfl_xor(a2[b], 1); a2[b] += __shfl_xor(a2[b], 2);
        }
        if (ks == 0) {
#pragma unroll
            for (int b = 0; b < 4; ++b) {
                part[par][wv][ul][0 * 4 + b] = a0[b];
                part[par][wv][ul][1 * 4 + b] = a1[b];
                part[par][wv][ul][2 * 4 + b] = a2[b];
            }
        }
        __syncthreads();   // S1 (only barrier per step): partials visible

        if (wv == 0) {
            double hv = hl[hvidx];   // read BEFORE publish; overwriter waits on our flag
            double s0 = part[par][0][u2][0 * 4 + b2] + part[par][1][u2][0 * 4 + b2]
                      + part[par][2][u2][0 * 4 + b2] + part[par][3][u2][0 * 4 + b2];
            double s1 = part[par][0][u2][1 * 4 + b2] + part[par][1][u2][1 * 4 + b2]
                      + part[par][2][u2][1 * 4 + b2] + part[par][3][u2][1 * 4 + b2];
            double s2 = part[par][0][u2][2 * 4 + b2] + part[par][1][u2][2 * 4 + b2]
                      + part[par][2][u2][2 * 4 + b2] + part[par][3][u2][2 * 4 + b2];
            double r  = 1.0 / (1.0 + exp(-(gr + s0 + bhr_)));
            double zt = 1.0 / (1.0 + exp(-(gz + s1 + bhz_)));
            double n  = tanh(gn + r * (s2 + bhn_));
            double hn_ = (1.0 - zt) * n + zt * hv;
            if (s < S_ - 1) {
                double* hdst = hglob + ((size_t)((s + 1) & 1)) * 16384 + (size_t)g * 2048;
                // (beta*16+u2)*4 + b2 == beta*64 + lane -> fully coalesced 512B store
                __hip_atomic_store((ull_*)&hdst[beta * 64 + lane],
                                   __builtin_bit_cast(ull_, hn_),
                                   __ATOMIC_RELAXED, __HIP_MEMORY_SCOPE_AGENT);
                if (lane == 0)
                    __hip_atomic_store(&flags[(g * 32 + beta) * FPAD], s + 1,
                                       __ATOMIC_RELEASE, __HIP_MEMORY_SCOPE_AGENT);
                // gi prefetch for s+1: after the flag so it doesn't delay it
                size_t gb = ((size_t)((s + 1) * 512 + u_g) * 3) * 32 + b_g;
                gr = gi[gb]; gz = gi[gb + 32]; gn = gi[gb + 64];
            }
            // outs store AFTER the release flag: keeps its scattered lines out
            // of the release's vmcnt drain (consumers don't need outs).
            outs[(size_t)(b_g * 64 + s) * H_ + u_g] = (s < len) ? (float)hn_ : 0.0f;
        }
        if (s == S_ - 1) break;

        // ---- per-wave poll: only this wave's 8 source-block flags ----
        {
            bool seen = (lane >= 8);
            while (!__all(seen)) {
                if (!seen)
                    seen = __hip_atomic_load(&flags[srcflag], __ATOMIC_RELAXED,
                                             __HIP_MEMORY_SCOPE_AGENT) >= s + 1;
                if (!__all(seen)) __builtin_amdgcn_s_sleep(1);
            }
        }
        asm volatile("" ::: "memory");
        // ---- per-wave restage of OWN 4KB slice; straight into next matvec ----
        {
            const ull_* hgu =
                (const ull_*)(hglob + ((size_t)((s + 1) & 1)) * 16384 + (size_t)g * 2048);
            ull_ tmp[8];
#pragma unroll
            for (int j = 0; j < 8; ++j)
                tmp[j] = __hip_atomic_load(&hgu[wv * 512 + j * 64 + lane],
                                           __ATOMIC_RELAXED, __HIP_MEMORY_SCOPE_AGENT);
            ull_* hlu = (ull_*)hl;
#pragma unroll
            for (int j = 0; j < 8; ++j) {
                int e = wv * 512 + j * 64 + lane;
                hlu[e + ((e >> 7) << 2)] = tmp[j];
            }
        }
        // no second barrier: each wave reads only its own slice in the matvec;
        // wave0's hv read is protected by the publish/poll dependency.
    }
}

// ---------------------------------------------------------------------------
// bf16 helpers + fused prep kernel: blocks [0,5000) convert W_out -> W16,
// blocks [5000,5512) convert outs -> A16.
// ---------------------------------------------------------------------------
__device__ __forceinline__ unsigned short f2b_(float x) {
    unsigned u = __builtin_bit_cast(unsigned, x);
    return (unsigned short)((u + 0x7FFFu + ((u >> 16) & 1u)) >> 16);   // RNE
}
__device__ __forceinline__ short8v pack8_(float4 a, float4 b) {
    short8v r;
    r[0] = (short)f2b_(a.x); r[1] = (short)f2b_(a.y);
    r[2] = (short)f2b_(a.z); r[3] = (short)f2b_(a.w);
    r[4] = (short)f2b_(b.x); r[5] = (short)f2b_(b.y);
    r[6] = (short)f2b_(b.z); r[7] = (short)f2b_(b.w);
    return r;
}
__global__ __launch_bounds__(256) void k_prep2(const float* __restrict__ Wsrc,
                                               const float* __restrict__ Asrc,
                                               short* __restrict__ W16,
                                               short* __restrict__ A16) {
    int bid = blockIdx.x, t = threadIdx.x;
    if (bid < 5000) {
        int i = bid * 256 + t;               // < 1,280,000
        float4 a = *(const float4*)&Wsrc[(size_t)i * 8];
        float4 b = *(const float4*)&Wsrc[(size_t)i * 8 + 4];
        *(short8v*)&W16[(size_t)i * 8] = pack8_(a, b);
    } else {
        int i = (bid - 5000) * 256 + t;      // < 131072
        float4 a = *(const float4*)&Asrc[(size_t)i * 8];
        float4 b = *(const float4*)&Asrc[(size_t)i * 8 + 4];
        *(short8v*)&A16[(size_t)i * 8] = pack8_(a, b);
    }
}

// ---------------------------------------------------------------------------
// K5: p = sigmoid(outs_bf16 @ W_bf16^T + b_out), bf16 MFMA. BK=64.
//     128x128 tile, 4 waves (2x2 of 64x64), LDS stride 72.
// ---------------------------------------------------------------------------
#define LDK5 72
__global__ __launch_bounds__(256, 2) void k5_mfma(const short* __restrict__ A16,  // 2048x512 bf16
                                                  const short* __restrict__ W16,  // 20000x512 bf16
                                                  const float* __restrict__ bo,
                                                  float* __restrict__ pOut) {
    __shared__ short As[128 * LDK5];   // 18.4KB
    __shared__ short Bs[128 * LDK5];
    int t = threadIdx.x;
    int bid = blockIdx.x;                       // 0..2511
    int swz = (bid & 7) * 314 + (bid >> 3);     // XCD swizzle (bijective, 2512=8*314)
    int m0 = (swz & 15) * 128;
    int n0 = (swz >> 4) * 128;
    int lane = t & 63, wv = t >> 6;
    int wr = wv >> 1, wc = wv & 1;              // wave -> 64x64 quadrant
    int ml = t >> 1;                            // 0..127 (staging row)
    int kl = (t & 1) * 32;                      // 0 or 32 (staging k-offset)

    const short* Arow = A16 + (size_t)(m0 + ml) * H_ + kl;
    int vrow = n0 + ml;
    bool vok = vrow < V_;
    const short* Wrow = W16 + (size_t)(vok ? vrow : 0) * H_ + kl;
    short8v zz = (short8v){0, 0, 0, 0, 0, 0, 0, 0};

    f32x4 acc[4][4];
#pragma unroll
    for (int i = 0; i < 4; ++i)
#pragma unroll
        for (int j = 0; j < 4; ++j) acc[i][j] = (f32x4){0.f, 0.f, 0.f, 0.f};

    int ko = lane >> 4;       // 0..3 (k-group of 8)
    int rr = lane & 15;       // fragment row/col

    for (int kt = 0; kt < H_; kt += 64) {
        short8v a0 = *(const short8v*)(Arow + kt);
        short8v a1 = *(const short8v*)(Arow + kt + 8);
        short8v a2 = *(const short8v*)(Arow + kt + 16);
        short8v a3 = *(const short8v*)(Arow + kt + 24);
        short8v b0 = vok ? *(const short8v*)(Wrow + kt) : zz;
        short8v b1 = vok ? *(const short8v*)(Wrow + kt + 8) : zz;
        short8v b2 = vok ? *(const short8v*)(Wrow + kt + 16) : zz;
        short8v b3 = vok ? *(const short8v*)(Wrow + kt + 24) : zz;
        *(short8v*)&As[ml * LDK5 + kl]      = a0;
        *(short8v*)&As[ml * LDK5 + kl + 8]  = a1;
        *(short8v*)&As[ml * LDK5 + kl + 16] = a2;
        *(short8v*)&As[ml * LDK5 + kl + 24] = a3;
        *(short8v*)&Bs[ml * LDK5 + kl]      = b0;
        *(short8v*)&Bs[ml * LDK5 + kl + 8]  = b1;
        *(short8v*)&Bs[ml * LDK5 + kl + 16] = b2;
        *(short8v*)&Bs[ml * LDK5 + kl + 24] = b3;
        __syncthreads();

#pragma unroll
        for (int kh = 0; kh < 2; ++kh) {
            short8v af[4], bf[4];
#pragma unroll
            for (int i = 0; i < 4; ++i)
                af[i] = *(const short8v*)&As[(wr * 64 + i * 16 + rr) * LDK5 + kh * 32 + ko * 8];
#pragma unroll
            for (int j = 0; j < 4; ++j)
                bf[j] = *(const short8v*)&Bs[(wc * 64 + j * 16 + rr) * LDK5 + kh * 32 + ko * 8];
#pragma unroll
            for (int i = 0; i < 4; ++i)
#pragma unroll
                for (int j = 0; j < 4; ++j)
                    acc[i][j] = __builtin_amdgcn_mfma_f32_16x16x32_bf16(af[i], bf[j], acc[i][j], 0, 0, 0);
        }
        __syncthreads();
    }

    int cr4 = (lane >> 4) * 4;
    float bov[4];
#pragma unroll
    for (int j = 0; j < 4; ++j) {
        int v = n0 + wc * 64 + j * 16 + rr;
        bov[j] = (v < V_) ? bo[v] : 0.f;
    }
#pragma unroll
    for (int i = 0; i < 4; ++i) {
#pragma unroll
        for (int j = 0; j < 4; ++j) {
            int v = n0 + wc * 64 + j * 16 + rr;
            if (v < V_) {
#pragma unroll
                for (int r = 0; r < 4; ++r) {
                    int m = m0 + wr * 64 + i * 16 + cr4 + r;
                    float x = acc[i][j][r] + bov[j];
                    pOut[(size_t)m * V_ + v] = 1.0f / (1.0f + expf(-x));
                }
            }
        }
    }
}

// ---------------------------------------------------------------------------
// K7a v2: per-wave top-32 via lazy-top-2 tournament. Candidates: 8x32=256/row.
// ---------------------------------------------------------------------------
__global__ __launch_bounds__(512) void k7a_cand(const float* __restrict__ pOut,
                                                float* __restrict__ candV,
                                                int* __restrict__ candI) {
    int row = blockIdx.x;
    int t = threadIdx.x;
    int wv = t >> 6;          // chunk 0..7 (2500 cols each)
    int lane = t & 63;
    const float* rowp = pOut + (size_t)row * V_ + wv * 2500;

    float rv[40];
#pragma unroll
    for (int q4 = 0; q4 < 10; ++q4) {
        int base = q4 * 256 + lane * 4;
        float4 v4 = *(const float4*)(rowp + base);   // tails stay inside d_out; masked below
        float vv[4] = {v4.x, v4.y, v4.z, v4.w};
#pragma unroll
        for (int c = 0; c < 4; ++c) {
            int li = base + c;
            int col = wv * 2500 + li;
            bool ok = (li < 2500) && (col >= 3);
            rv[q4 * 4 + c] = ok ? vv[c] : NEG7;
        }
    }
    float m1 = rv[0]; int s1 = 0;
#pragma unroll
    for (int q = 1; q < 40; ++q)
        if (rv[q] > m1) { m1 = rv[q]; s1 = q; }
    float m2 = NEG7; int s2 = 0;
#pragma unroll
    for (int q = 0; q < 40; ++q)
        if (q != s1 && rv[q] > m2) { m2 = rv[q]; s2 = q; }
    bool dirty = false;
    ull_ used = 0;
    int myidx = wv * 2500 + (s1 >> 2) * 256 + lane * 4 + (s1 & 3);

    float keepv = NEG7; int keepi = 0;
#pragma unroll 1
    for (int r = 0; r < 32; ++r) {
        float bv = m1; int bi = myidx;
#pragma unroll
        for (int m = 1; m < 64; m <<= 1) {
            float ov = __shfl_xor(bv, m);
            int   oi = __shfl_xor(bi, m);
            if (ov > bv || (ov == bv && oi < bi)) { bv = ov; bi = oi; }
        }
        if (lane == r) { keepv = bv; keepi = bi; }
        if (myidx == bi) {           // this lane won (idx unique -> exactly one)
            used |= (1ull << s1);
            if (!dirty) {
                m1 = m2; s1 = s2; dirty = true;
            } else {
                m1 = NEG7; s1 = 0;
#pragma unroll
                for (int q = 0; q < 40; ++q) {
                    float v = ((used >> q) & 1ull) ? NEG7 : rv[q];
                    if (v > m1) { m1 = v; s1 = q; }
                }
                m2 = NEG7; s2 = 0;
#pragma unroll
                for (int q = 0; q < 40; ++q) {
                    float v = (((used >> q) & 1ull) || q == s1) ? NEG7 : rv[q];
                    if (v > m2) { m2 = v; s2 = q; }
                }
                dirty = false;
            }
            myidx = wv * 2500 + (s1 >> 2) * 256 + lane * 4 + (s1 & 3);
        }
    }
    if (lane < 32) {
        size_t o = ((size_t)row * 8 + wv) * 32 + lane;
        candV[o] = keepv;
        candI[o] = keepi;
    }
}

// ---------------------------------------------------------------------------
// K7b: merge 256 candidates -> global top-64 (stable); f64 rescore; final
//     top-30 by (rescored desc, idx asc). Also computes m_output (fused k6).
// ---------------------------------------------------------------------------
__global__ __launch_bounds__(256) void k7b_final(const float* __restrict__ candV,
                                                 const int* __restrict__ candI,
                                                 const float* __restrict__ outs,
                                                 const float* __restrict__ W,
                                                 const float* __restrict__ bo,
                                                 float* __restrict__ mOut,
                                                 float* __restrict__ sOut) {
    __shared__ float selv[64];
    __shared__ int   seli[64];
    __shared__ float resv[64];
    __shared__ float redm[4];
    __shared__ __align__(16) float orow[H_];

    int row = blockIdx.x;
    int t = threadIdx.x;
    int lane = t & 63, wid = t >> 6;

    if (wid != 0) {
        for (int i = t - 64; i < H_; i += 192)
            orow[i] = outs[(size_t)row * H_ + i];
    } else {
        float cv[4]; int ci[4];
#pragma unroll
        for (int q = 0; q < 4; ++q) {
            size_t o = (size_t)row * 256 + q * 64 + lane;
            cv[q] = candV[o];
            ci[q] = candI[o];
        }
        float lv = cv[0]; int lix = ci[0]; int ls = 0;
#pragma unroll
        for (int q = 1; q < 4; ++q)
            if (cv[q] > lv || (cv[q] == lv && ci[q] < lix)) { lv = cv[q]; lix = ci[q]; ls = q; }

#pragma unroll 1
        for (int r = 0; r < 64; ++r) {
            float bv = lv; int bi = lix;
#pragma unroll
            for (int m = 1; m < 64; m <<= 1) {
                float ov = __shfl_xor(bv, m);
                int   oi = __shfl_xor(bi, m);
                if (ov > bv || (ov == bv && oi < bi)) { bv = ov; bi = oi; }
            }
            if (lane == r) { selv[r] = bv; seli[r] = bi; }
            if (lix == bi) {
#pragma unroll
                for (int q = 0; q < 4; ++q) cv[q] = (ls == q) ? NEG7 : cv[q];
                lv = cv[0]; lix = ci[0]; ls = 0;
#pragma unroll
                for (int q = 1; q < 4; ++q)
                    if (cv[q] > lv || (cv[q] == lv && ci[q] < lix)) { lv = cv[q]; lix = ci[q]; ls = q; }
            }
        }
    }
    __syncthreads();

    {
        float ms = fabsf(orow[t]) + fabsf(orow[t + 256]);
#pragma unroll
        for (int m = 1; m < 64; m <<= 1) ms += __shfl_xor(ms, m);
        if (lane == 0) redm[wid] = ms;
    }

    {
        int c = t >> 2, q = t & 3;
        int gidx = seli[c];
        const float4* w4 = (const float4*)(W + (size_t)gidx * H_);
        const float4* o4 = (const float4*)orow;
        double acc = 0.0;
#pragma unroll 8
        for (int i2 = 0; i2 < 32; ++i2) {
            float4 wv4 = w4[i2 * 4 + q];
            float4 ov4 = o4[i2 * 4 + q];
            acc += (double)wv4.x * (double)ov4.x + (double)wv4.y * (double)ov4.y
                 + (double)wv4.z * (double)ov4.z + (double)wv4.w * (double)ov4.w;
        }
        acc += __shfl_xor(acc, 1);
        acc += __shfl_xor(acc, 2);
        if (q == 0) resv[c] = (float)(acc + (double)bo[gidx]);
    }
    __syncthreads();

    if (t == 0)
        mOut[row] = (redm[0] + redm[1] + redm[2] + redm[3] > 0.f) ? 1.f : 0.f;

    if (t < 64) {
        float v = resv[t];
        int idx = seli[t];
#pragma unroll 1
        for (int r = 0; r < MV_; ++r) {
            float bv = v; int bi = idx;
#pragma unroll
            for (int m = 1; m < 64; m <<= 1) {
                float ov = __shfl_xor(bv, m);
                int   oi = __shfl_xor(bi, m);
                if (ov > bv || (ov == bv && oi < bi)) { bv = ov; bi = oi; }
            }
            if (t == 0)
                sOut[(size_t)row * MV_ + r] = (bv <= 0.0f) ? 0.0f : (float)bi;
            if (idx == bi) v = NEG7;
        }
    }
}

// ---------------------------------------------------------------------------
extern "C" void kernel_launch(void* const* d_in, const int* in_sizes, int n_in,
                              void* d_out, int out_size, void* d_ws, size_t ws_size,
                              hipStream_t stream) {
    const float* z      = (const float*)d_in[0];
    const int*   seq    = (const int*)d_in[1];
    const int*   length = (const int*)d_in[2];
    const float* Ew     = (const float*)d_in[3];
    const float* W_l2h  = (const float*)d_in[4];
    const float* b_l2h  = (const float*)d_in[5];
    const float* W_ih   = (const float*)d_in[6];
    const float* W_hh   = (const float*)d_in[7];
    const float* b_ih   = (const float*)d_in[8];
    const float* b_hh   = (const float*)d_in[9];
    const float* W_out  = (const float*)d_in[10];
    const float* b_out  = (const float*)d_in[11];

    float* out = (float*)d_out;

    double* emb_d = (double*)d_ws;               // 2048*256 f64 (A16 overlay after k4)
    double* gi_d  = emb_d + 524288;              // 2048*1536 f64 (W16 overlay after k4)
    double* hglob = gi_d + 3145728;              // 2 x 16384 f64 (parity h, grouped packing)
    float*  outs  = (float*)(hglob + 32768);     // 2048*512 f32
    int*    flags = (int*)(outs + 1048576);      // NB4*FPAD ints
    float*  candV = (float*)(flags + NB4 * FPAD);        // 2048*256 f32
    int*    candI = (int*)(candV + (size_t)BS_ * 256);   // 2048*256 i32
    short*  A16   = (short*)emb_d;               // 2048*512 bf16 (emb dead after k4)
    short*  W16   = (short*)gi_d;                // 20000*512 bf16 (gi dead after k4)

    float* pOut = out;                           // 2048*20000
    float* sOut = out + (size_t)BS_ * V_;        // 2048*30
    float* mOut = sOut + (size_t)BS_ * MV_;      // 2048

    k12<<<BS_ + 65, 256, 0, stream>>>(seq, Ew, z, W_l2h, b_l2h, emb_d, hglob, flags);
    k3_gi<<<dim3(24, 32), 256, 0, stream>>>(emb_d, W_ih, b_ih, gi_d);
    k4_gru<<<NB4, 256, 0, stream>>>(gi_d, W_hh, b_hh, length, hglob, outs, flags);
    k_prep2<<<5512, 256, 0, stream>>>(W_out, outs, W16, A16);
    k5_mfma<<<2512, 256, 0, stream>>>(A16, W16, b_out, pOut);
    k7a_cand<<<BS_, 512, 0, stream>>>(pOut, candV, candI);
    k7b_final<<<BS_, 256, 0, stream>>>(candV, candI, outs, W_out, b_out, mOut, sOut);
}

// Round 5
// 658.581 us; speedup vs baseline: 1.5099x; 1.2195x over previous
//
#include <hip/hip_runtime.h>
#include <hip/hip_bf16.h>
#include <math.h>

// Problem constants
#define B_ 32
#define S_ 64
#define MV_ 30
#define V_ 20000
#define E_ 256
#define H_ 512
#define L_ 128
#define H3_ 1536
#define BS_ 2048   // B*S
#define NB4 256    // k4 grid blocks (persistent, co-resident; 8 groups x 32)
#define NEG7 -3.0e38f
#define SENT 0xFFF8000000000000ULL   // quiet NaN; h is always finite -> unreachable

typedef __attribute__((ext_vector_type(8))) short short8v;  // 8 bf16 (4 VGPRs)
typedef __attribute__((ext_vector_type(4))) float f32x4;
typedef unsigned long long ull_;

// ---------------------------------------------------------------------------
// K12: blocks [0,2048): k1 multi-hot embed body (verbatim);
//      blocks [2048,2112): k2 h0 body (grouped packing, step-0 buffer);
//      blocks [2112,3120): NaN-sentinel init of step buffers 1..63 (8.25MB).
// hstep layout: hstep[s*16384 + g*2048 + u*4 + b_in_group], s = 0..63
// ---------------------------------------------------------------------------
__global__ __launch_bounds__(256) void k12(const int* __restrict__ seq,
                                           const float* __restrict__ Ew,
                                           const float* __restrict__ z,
                                           const float* __restrict__ Wl,
                                           const float* __restrict__ bl,
                                           double* __restrict__ emb,
                                           double* __restrict__ hstep) {
    __shared__ int sidx[MV_];
    int bid = blockIdx.x;
    int t = threadIdx.x;
    if (bid < BS_) {
        int row = bid;
        if (t < MV_) sidx[t] = seq[row * MV_ + t];
        __syncthreads();
        double acc = 0.0;
        for (int i = 0; i < MV_; ++i) {
            int id = sidx[i];
            if (id == 0) continue;
            bool dup = false;
            for (int q = 0; q < i; ++q) dup = dup || (sidx[q] == id);
            if (!dup) acc += (double)Ew[(size_t)id * E_ + t];
        }
        emb[(size_t)row * E_ + t] = tanh(acc);
    } else if (bid < BS_ + 64) {
        int o = (bid - BS_) * 256 + t;   // < 16384
        int b = o >> 9;
        int j = o & 511;
        const float4* zr = (const float4*)(z + (size_t)b * L_);
        const float4* wr = (const float4*)(Wl + (size_t)j * L_);
        double acc = (double)bl[j];
#pragma unroll
        for (int k = 0; k < L_ / 4; ++k) {
            float4 a = zr[k];
            float4 w = wr[k];
            acc += (double)a.x * (double)w.x + (double)a.y * (double)w.y
                 + (double)a.z * (double)w.z + (double)a.w * (double)w.w;
        }
        hstep[(size_t)(b >> 2) * 2048 + j * 4 + (b & 3)] = acc;
    } else {
        // sentinel fill for steps 1..63: 63*16384 = 1,032,192 ulls
        ull_* hs = (ull_*)hstep;
        size_t i = (size_t)(bid - (BS_ + 64)) * 1024 + (size_t)t * 4;
        hs[16384 + i + 0] = SENT;
        hs[16384 + i + 1] = SENT;
        hs[16384 + i + 2] = SENT;
        hs[16384 + i + 3] = SENT;
    }
}

// ---------------------------------------------------------------------------
// K3: Gi = emb @ W_ih^T + b_ih  (2048x1536, K=256), f64. 64x64 tile, 4x4/thread.
//     Output PACKED for k4: gi_p[(((s*512 + unit)*3 + gate)*32 + b)]
// ---------------------------------------------------------------------------
__global__ __launch_bounds__(256) void k3_gi(const double* __restrict__ A,
                                             const float* __restrict__ Bm,
                                             const float* __restrict__ bih,
                                             double* __restrict__ gi) {
    __shared__ double As[16][66];
    __shared__ double Bs[16][66];
    int t = threadIdx.x;
    int n0 = blockIdx.x * 64;   // 24
    int m0 = blockIdx.y * 64;   // 32
    int tx = t & 15, ty = t >> 4;
    int ml = t >> 2;
    int kl = (t & 3) * 4;
    double acc[4][4];
#pragma unroll
    for (int i = 0; i < 4; ++i)
#pragma unroll
        for (int j = 0; j < 4; ++j) acc[i][j] = 0.0;

    for (int kt = 0; kt < 256; kt += 16) {
        double4 av = *(const double4*)(A + (size_t)(m0 + ml) * 256 + kt + kl);
        float4 bv = *(const float4*)(Bm + (size_t)(n0 + ml) * 256 + kt + kl);
        As[kl + 0][ml] = av.x; As[kl + 1][ml] = av.y; As[kl + 2][ml] = av.z; As[kl + 3][ml] = av.w;
        Bs[kl + 0][ml] = (double)bv.x; Bs[kl + 1][ml] = (double)bv.y;
        Bs[kl + 2][ml] = (double)bv.z; Bs[kl + 3][ml] = (double)bv.w;
        __syncthreads();
#pragma unroll
        for (int kk = 0; kk < 16; ++kk) {
            double2 a01 = *(const double2*)&As[kk][ty * 4];
            double2 a23 = *(const double2*)&As[kk][ty * 4 + 2];
            double2 b01 = *(const double2*)&Bs[kk][tx * 4];
            double2 b23 = *(const double2*)&Bs[kk][tx * 4 + 2];
            double am[4] = {a01.x, a01.y, a23.x, a23.y};
            double bn[4] = {b01.x, b01.y, b23.x, b23.y};
#pragma unroll
            for (int i = 0; i < 4; ++i)
#pragma unroll
                for (int j = 0; j < 4; ++j) acc[i][j] += am[i] * bn[j];
        }
        __syncthreads();
    }
#pragma unroll
    for (int i = 0; i < 4; ++i) {
        int m = m0 + ty * 4 + i;
        int bb = m >> 6, ss = m & 63;
#pragma unroll
        for (int j = 0; j < 4; ++j) {
            int n = n0 + tx * 4 + j;
            int g = n >> 9, u = n & 511;
            gi[(((size_t)(ss * 512 + u)) * 3 + g) * 32 + bb] = acc[i][j] + (double)bih[n];
        }
    }
}

// ---------------------------------------------------------------------------
// K4 (round-14): persistent cooperative GRU, SENTINEL DATA-POLL sync.
//   Geometry unchanged from round-13 (8 groups x 32 blocks; block beta owns
//   units beta*16..+16; W_hh in registers; wave wv owns k in [128wv,+128)).
//   NEW: per-step publish buffers hstep[s] (NaN-prefilled). Publish = plain
//   relaxed agent-scope 8B stores (no release, no vmcnt drain, no flags).
//   Consumers poll THE DATA ITSELF for non-NaN: one LLC round trip instead of
//   (h-drain -> flag store -> flag visibility -> h load). h_prev lives in a
//   register (hv) so no hl ordering constraint; step buffers are write-once so
//   arbitrary inter-block skew is safe; parity part[] covers intra-block skew.
//   All arithmetic bit-identical to round-13.
// ---------------------------------------------------------------------------
__global__ __launch_bounds__(256, 1) void k4_gru(const double* __restrict__ gi,
                                                 const float* __restrict__ whh,
                                                 const float* __restrict__ bhh,
                                                 const int* __restrict__ length,
                                                 double* __restrict__ hstep,
                                                 float* __restrict__ outs) {
    __shared__ double hl[2112];               // group h: idx = e + (e>>7)*4
    __shared__ double part[2][4][16][13];     // [parity][wave][ul][gate*4+b], pad 13

    int t = threadIdx.x;
    int wv = t >> 6;
    int lane = t & 63;
    int bid = blockIdx.x;
    int g = bid & 7;          // group
    int beta = bid >> 3;      // block-in-group 0..31

    // matvec lane mapping: (ul, ks); wave wv covers k in [wv*128, wv*128+128)
    int ul = lane >> 2, ks = lane & 3;

    // ---- W_hh slice into registers: rows (gate*512 + beta*16 + ul),
    //      cols [wv*128 + ks*32, +32) = 8 float4 per gate ----
    const float* wbase = whh + ((size_t)(beta * 16 + ul)) * 512 + wv * 128 + ks * 32;
    float4 w0r[8], w1r[8], w2r[8];
#pragma unroll
    for (int c = 0; c < 8; ++c) {
        w0r[c] = *(const float4*)(wbase + c * 4);
        w1r[c] = *(const float4*)(wbase + 512 * 512 + c * 4);
        w2r[c] = *(const float4*)(wbase + 1024 * 512 + c * 4);
    }

    // ---- initial h (step 0), group-local 16KB (plain loads; pre-k4 data) ----
    const double* hg0 = hstep + (size_t)g * 2048;
    {
#pragma unroll
        for (int j = 0; j < 8; ++j) {
            int e = t + j * 256;
            hl[e + ((e >> 7) << 2)] = hg0[e];
        }
    }
    __syncthreads();

    // wave0 per-lane elementwise state: lane = (u2 0..15, b2 0..3)
    int u2 = lane >> 2, b2 = lane & 3;
    int u_g = beta * 16 + u2;      // global unit
    int b_g = g * 4 + b2;          // global batch
    double gr = 0.0, gz = 0.0, gn = 0.0, bhr_ = 0.0, bhz_ = 0.0, bhn_ = 0.0;
    double hv = 0.0;               // own h_prev in register
    int len = 0;
    if (wv == 0) {
        bhr_ = (double)bhh[u_g];
        bhz_ = (double)bhh[u_g + 512];
        bhn_ = (double)bhh[u_g + 1024];
        len = length[b_g];
        hv = hg0[u_g * 4 + b2];
        size_t gb = ((size_t)u_g * 3) * 32 + b_g;
        gr = gi[gb]; gz = gi[gb + 32]; gn = gi[gb + 64];
    }

    const double* hr = &hl[(wv * 128 + ks * 32) * 4 + ((wv * 4 + ks) << 2)];

    for (int s = 0; s < S_; ++s) {
        int par = s & 1;
        double a0[4] = {0, 0, 0, 0}, a1[4] = {0, 0, 0, 0}, a2[4] = {0, 0, 0, 0};
#pragma unroll
        for (int c = 0; c < 8; ++c) {
            const double* hp = hr + c * 16;
            double2 hA0 = *(const double2*)(hp + 0),  hB0 = *(const double2*)(hp + 2);
            double2 hA1 = *(const double2*)(hp + 4),  hB1 = *(const double2*)(hp + 6);
            double2 hA2 = *(const double2*)(hp + 8),  hB2 = *(const double2*)(hp + 10);
            double2 hA3 = *(const double2*)(hp + 12), hB3 = *(const double2*)(hp + 14);
            float4 w0 = w0r[c], w1 = w1r[c], w2 = w2r[c];
            // j = 0
            { double d0 = (double)w0.x, d1 = (double)w1.x, d2 = (double)w2.x;
              a0[0] += hA0.x * d0; a0[1] += hA0.y * d0; a0[2] += hB0.x * d0; a0[3] += hB0.y * d0;
              a1[0] += hA0.x * d1; a1[1] += hA0.y * d1; a1[2] += hB0.x * d1; a1[3] += hB0.y * d1;
              a2[0] += hA0.x * d2; a2[1] += hA0.y * d2; a2[2] += hB0.x * d2; a2[3] += hB0.y * d2; }
            // j = 1
            { double d0 = (double)w0.y, d1 = (double)w1.y, d2 = (double)w2.y;
              a0[0] += hA1.x * d0; a0[1] += hA1.y * d0; a0[2] += hB1.x * d0; a0[3] += hB1.y * d0;
              a1[0] += hA1.x * d1; a1[1] += hA1.y * d1; a1[2] += hB1.x * d1; a1[3] += hB1.y * d1;
              a2[0] += hA1.x * d2; a2[1] += hA1.y * d2; a2[2] += hB1.x * d2; a2[3] += hB1.y * d2; }
            // j = 2
            { double d0 = (double)w0.z, d1 = (double)w1.z, d2 = (double)w2.z;
              a0[0] += hA2.x * d0; a0[1] += hA2.y * d0; a0[2] += hB2.x * d0; a0[3] += hB2.y * d0;
              a1[0] += hA2.x * d1; a1[1] += hA2.y * d1; a1[2] += hB2.x * d1; a1[3] += hB2.y * d1;
              a2[0] += hA2.x * d2; a2[1] += hA2.y * d2; a2[2] += hB2.x * d2; a2[3] += hB2.y * d2; }
            // j = 3
            { double d0 = (double)w0.w, d1 = (double)w1.w, d2 = (double)w2.w;
              a0[0] += hA3.x * d0; a0[1] += hA3.y * d0; a0[2] += hB3.x * d0; a0[3] += hB3.y * d0;
              a1[0] += hA3.x * d1; a1[1] += hA3.y * d1; a1[2] += hB3.x * d1; a1[3] += hB3.y * d1;
              a2[0] += hA3.x * d2; a2[1] += hA3.y * d2; a2[2] += hB3.x * d2; a2[3] += hB3.y * d2; }
        }
        // reduce over ks (lanes xor 1, 2)
#pragma unroll
        for (int b = 0; b < 4; ++b) {
            a0[b] += __shfl_xor(a0[b], 1); a0[b] += __shfl_xor(a0[b], 2);
            a1[b] += __shfl_xor(a1[b], 1); a1[b] += __shfl_xor(a1[b], 2);
            a2[b] += __shfl_xor(a2[b], 1); a2[b] += __shfl_xor(a2[b], 2);
        }
        if (ks == 0) {
#pragma unroll
            for (int b = 0; b < 4; ++b) {
                part[par][wv][ul][0 * 4 + b] = a0[b];
                part[par][wv][ul][1 * 4 + b] = a1[b];
                part[par][wv][ul][2 * 4 + b] = a2[b];
            }
        }
        __syncthreads();   // S1 (only barrier per step): partials visible

        if (wv == 0) {
            double s0 = part[par][0][u2][0 * 4 + b2] + part[par][1][u2][0 * 4 + b2]
                      + part[par][2][u2][0 * 4 + b2] + part[par][3][u2][0 * 4 + b2];
            double s1 = part[par][0][u2][1 * 4 + b2] + part[par][1][u2][1 * 4 + b2]
                      + part[par][2][u2][1 * 4 + b2] + part[par][3][u2][1 * 4 + b2];
            double s2 = part[par][0][u2][2 * 4 + b2] + part[par][1][u2][2 * 4 + b2]
                      + part[par][2][u2][2 * 4 + b2] + part[par][3][u2][2 * 4 + b2];
            double r  = 1.0 / (1.0 + exp(-(gr + s0 + bhr_)));
            double zt = 1.0 / (1.0 + exp(-(gz + s1 + bhz_)));
            double n  = tanh(gn + r * (s2 + bhn_));
            double hn_ = (1.0 - zt) * n + zt * hv;
            hv = hn_;
            if (s < S_ - 1) {
                // publish to write-once step buffer; the data IS the flag
                ull_* hdst = (ull_*)(hstep + (size_t)(s + 1) * 16384 + (size_t)g * 2048);
                // (beta*16+u2)*4 + b2 == beta*64 + lane -> fully coalesced 512B store
                __hip_atomic_store(&hdst[beta * 64 + lane],
                                   __builtin_bit_cast(ull_, hn_),
                                   __ATOMIC_RELAXED, __HIP_MEMORY_SCOPE_AGENT);
                // gi prefetch for s+1 (overlaps consumers' polls)
                size_t gb = ((size_t)((s + 1) * 512 + u_g) * 3) * 32 + b_g;
                gr = gi[gb]; gz = gi[gb + 32]; gn = gi[gb + 64];
            }
            outs[(size_t)(b_g * 64 + s) * H_ + u_g] = (s < len) ? (float)hn_ : 0.0f;
        }
        if (s == S_ - 1) break;

        // ---- per-wave data-poll + restage of OWN 4KB slice ----
        {
            const ull_* src = (const ull_*)(hstep + (size_t)(s + 1) * 16384
                                            + (size_t)g * 2048) + wv * 512;
            ull_ tmp[8];
            while (true) {
                bool ok = true;
#pragma unroll
                for (int j = 0; j < 8; ++j) {
                    tmp[j] = __hip_atomic_load(&src[j * 64 + lane],
                                               __ATOMIC_RELAXED, __HIP_MEMORY_SCOPE_AGENT);
                    ok = ok && (tmp[j] != SENT);
                }
                if (__all(ok)) break;
                __builtin_amdgcn_s_sleep(1);
            }
            asm volatile("" ::: "memory");
            ull_* hlu = (ull_*)hl;
#pragma unroll
            for (int j = 0; j < 8; ++j) {
                int e = wv * 512 + j * 64 + lane;
                hlu[e + ((e >> 7) << 2)] = tmp[j];
            }
        }
        // no second barrier: each wave reads only its own slice in the matvec
        // (round-12/13-proven same-wave ds_write -> cross-lane ds_read pattern).
    }
}

// ---------------------------------------------------------------------------
// bf16 helpers + fused prep kernel: blocks [0,5000) convert W_out -> W16,
// blocks [5000,5512) convert outs -> A16.
// ---------------------------------------------------------------------------
__device__ __forceinline__ unsigned short f2b_(float x) {
    unsigned u = __builtin_bit_cast(unsigned, x);
    return (unsigned short)((u + 0x7FFFu + ((u >> 16) & 1u)) >> 16);   // RNE
}
__device__ __forceinline__ short8v pack8_(float4 a, float4 b) {
    short8v r;
    r[0] = (short)f2b_(a.x); r[1] = (short)f2b_(a.y);
    r[2] = (short)f2b_(a.z); r[3] = (short)f2b_(a.w);
    r[4] = (short)f2b_(b.x); r[5] = (short)f2b_(b.y);
    r[6] = (short)f2b_(b.z); r[7] = (short)f2b_(b.w);
    return r;
}
__global__ __launch_bounds__(256) void k_prep2(const float* __restrict__ Wsrc,
                                               const float* __restrict__ Asrc,
                                               short* __restrict__ W16,
                                               short* __restrict__ A16) {
    int bid = blockIdx.x, t = threadIdx.x;
    if (bid < 5000) {
        int i = bid * 256 + t;               // < 1,280,000
        float4 a = *(const float4*)&Wsrc[(size_t)i * 8];
        float4 b = *(const float4*)&Wsrc[(size_t)i * 8 + 4];
        *(short8v*)&W16[(size_t)i * 8] = pack8_(a, b);
    } else {
        int i = (bid - 5000) * 256 + t;      // < 131072
        float4 a = *(const float4*)&Asrc[(size_t)i * 8];
        float4 b = *(const float4*)&Asrc[(size_t)i * 8 + 4];
        *(short8v*)&A16[(size_t)i * 8] = pack8_(a, b);
    }
}

// ---------------------------------------------------------------------------
// K5: p = sigmoid(outs_bf16 @ W_bf16^T + b_out), bf16 MFMA. BK=64.
//     128x128 tile, 4 waves (2x2 of 64x64), LDS stride 72.
// ---------------------------------------------------------------------------
#define LDK5 72
__global__ __launch_bounds__(256, 2) void k5_mfma(const short* __restrict__ A16,  // 2048x512 bf16
                                                  const short* __restrict__ W16,  // 20000x512 bf16
                                                  const float* __restrict__ bo,
                                                  float* __restrict__ pOut) {
    __shared__ short As[128 * LDK5];   // 18.4KB
    __shared__ short Bs[128 * LDK5];
    int t = threadIdx.x;
    int bid = blockIdx.x;                       // 0..2511
    int swz = (bid & 7) * 314 + (bid >> 3);     // XCD swizzle (bijective, 2512=8*314)
    int m0 = (swz & 15) * 128;
    int n0 = (swz >> 4) * 128;
    int lane = t & 63, wv = t >> 6;
    int wr = wv >> 1, wc = wv & 1;              // wave -> 64x64 quadrant
    int ml = t >> 1;                            // 0..127 (staging row)
    int kl = (t & 1) * 32;                      // 0 or 32 (staging k-offset)

    const short* Arow = A16 + (size_t)(m0 + ml) * H_ + kl;
    int vrow = n0 + ml;
    bool vok = vrow < V_;
    const short* Wrow = W16 + (size_t)(vok ? vrow : 0) * H_ + kl;
    short8v zz = (short8v){0, 0, 0, 0, 0, 0, 0, 0};

    f32x4 acc[4][4];
#pragma unroll
    for (int i = 0; i < 4; ++i)
#pragma unroll
        for (int j = 0; j < 4; ++j) acc[i][j] = (f32x4){0.f, 0.f, 0.f, 0.f};

    int ko = lane >> 4;       // 0..3 (k-group of 8)
    int rr = lane & 15;       // fragment row/col

    for (int kt = 0; kt < H_; kt += 64) {
        short8v a0 = *(const short8v*)(Arow + kt);
        short8v a1 = *(const short8v*)(Arow + kt + 8);
        short8v a2 = *(const short8v*)(Arow + kt + 16);
        short8v a3 = *(const short8v*)(Arow + kt + 24);
        short8v b0 = vok ? *(const short8v*)(Wrow + kt) : zz;
        short8v b1 = vok ? *(const short8v*)(Wrow + kt + 8) : zz;
        short8v b2 = vok ? *(const short8v*)(Wrow + kt + 16) : zz;
        short8v b3 = vok ? *(const short8v*)(Wrow + kt + 24) : zz;
        *(short8v*)&As[ml * LDK5 + kl]      = a0;
        *(short8v*)&As[ml * LDK5 + kl + 8]  = a1;
        *(short8v*)&As[ml * LDK5 + kl + 16] = a2;
        *(short8v*)&As[ml * LDK5 + kl + 24] = a3;
        *(short8v*)&Bs[ml * LDK5 + kl]      = b0;
        *(short8v*)&Bs[ml * LDK5 + kl + 8]  = b1;
        *(short8v*)&Bs[ml * LDK5 + kl + 16] = b2;
        *(short8v*)&Bs[ml * LDK5 + kl + 24] = b3;
        __syncthreads();

#pragma unroll
        for (int kh = 0; kh < 2; ++kh) {
            short8v af[4], bf[4];
#pragma unroll
            for (int i = 0; i < 4; ++i)
                af[i] = *(const short8v*)&As[(wr * 64 + i * 16 + rr) * LDK5 + kh * 32 + ko * 8];
#pragma unroll
            for (int j = 0; j < 4; ++j)
                bf[j] = *(const short8v*)&Bs[(wc * 64 + j * 16 + rr) * LDK5 + kh * 32 + ko * 8];
#pragma unroll
            for (int i = 0; i < 4; ++i)
#pragma unroll
                for (int j = 0; j < 4; ++j)
                    acc[i][j] = __builtin_amdgcn_mfma_f32_16x16x32_bf16(af[i], bf[j], acc[i][j], 0, 0, 0);
        }
        __syncthreads();
    }

    int cr4 = (lane >> 4) * 4;
    float bov[4];
#pragma unroll
    for (int j = 0; j < 4; ++j) {
        int v = n0 + wc * 64 + j * 16 + rr;
        bov[j] = (v < V_) ? bo[v] : 0.f;
    }
#pragma unroll
    for (int i = 0; i < 4; ++i) {
#pragma unroll
        for (int j = 0; j < 4; ++j) {
            int v = n0 + wc * 64 + j * 16 + rr;
            if (v < V_) {
#pragma unroll
                for (int r = 0; r < 4; ++r) {
                    int m = m0 + wr * 64 + i * 16 + cr4 + r;
                    float x = acc[i][j][r] + bov[j];
                    pOut[(size_t)m * V_ + v] = 1.0f / (1.0f + expf(-x));
                }
            }
        }
    }
}

// ---------------------------------------------------------------------------
// K7a v2: per-wave top-32 via lazy-top-2 tournament. Candidates: 8x32=256/row.
// ---------------------------------------------------------------------------
__global__ __launch_bounds__(512) void k7a_cand(const float* __restrict__ pOut,
                                                float* __restrict__ candV,
                                                int* __restrict__ candI) {
    int row = blockIdx.x;
    int t = threadIdx.x;
    int wv = t >> 6;          // chunk 0..7 (2500 cols each)
    int lane = t & 63;
    const float* rowp = pOut + (size_t)row * V_ + wv * 2500;

    float rv[40];
#pragma unroll
    for (int q4 = 0; q4 < 10; ++q4) {
        int base = q4 * 256 + lane * 4;
        float4 v4 = *(const float4*)(rowp + base);   // tails stay inside d_out; masked below
        float vv[4] = {v4.x, v4.y, v4.z, v4.w};
#pragma unroll
        for (int c = 0; c < 4; ++c) {
            int li = base + c;
            int col = wv * 2500 + li;
            bool ok = (li < 2500) && (col >= 3);
            rv[q4 * 4 + c] = ok ? vv[c] : NEG7;
        }
    }
    float m1 = rv[0]; int s1 = 0;
#pragma unroll
    for (int q = 1; q < 40; ++q)
        if (rv[q] > m1) { m1 = rv[q]; s1 = q; }
    float m2 = NEG7; int s2 = 0;
#pragma unroll
    for (int q = 0; q < 40; ++q)
        if (q != s1 && rv[q] > m2) { m2 = rv[q]; s2 = q; }
    bool dirty = false;
    ull_ used = 0;
    int myidx = wv * 2500 + (s1 >> 2) * 256 + lane * 4 + (s1 & 3);

    float keepv = NEG7; int keepi = 0;
#pragma unroll 1
    for (int r = 0; r < 32; ++r) {
        float bv = m1; int bi = myidx;
#pragma unroll
        for (int m = 1; m < 64; m <<= 1) {
            float ov = __shfl_xor(bv, m);
            int   oi = __shfl_xor(bi, m);
            if (ov > bv || (ov == bv && oi < bi)) { bv = ov; bi = oi; }
        }
        if (lane == r) { keepv = bv; keepi = bi; }
        if (myidx == bi) {           // this lane won (idx unique -> exactly one)
            used |= (1ull << s1);
            if (!dirty) {
                m1 = m2; s1 = s2; dirty = true;
            } else {
                m1 = NEG7; s1 = 0;
#pragma unroll
                for (int q = 0; q < 40; ++q) {
                    float v = ((used >> q) & 1ull) ? NEG7 : rv[q];
                    if (v > m1) { m1 = v; s1 = q; }
                }
                m2 = NEG7; s2 = 0;
#pragma unroll
                for (int q = 0; q < 40; ++q) {
                    float v = (((used >> q) & 1ull) || q == s1) ? NEG7 : rv[q];
                    if (v > m2) { m2 = v; s2 = q; }
                }
                dirty = false;
            }
            myidx = wv * 2500 + (s1 >> 2) * 256 + lane * 4 + (s1 & 3);
        }
    }
    if (lane < 32) {
        size_t o = ((size_t)row * 8 + wv) * 32 + lane;
        candV[o] = keepv;
        candI[o] = keepi;
    }
}

// ---------------------------------------------------------------------------
// K7b: merge 256 candidates -> global top-64 (stable); f64 rescore; final
//     top-30 by (rescored desc, idx asc). Also computes m_output (fused k6).
// ---------------------------------------------------------------------------
__global__ __launch_bounds__(256) void k7b_final(const float* __restrict__ candV,
                                                 const int* __restrict__ candI,
                                                 const float* __restrict__ outs,
                                                 const float* __restrict__ W,
                                                 const float* __restrict__ bo,
                                                 float* __restrict__ mOut,
                                                 float* __restrict__ sOut) {
    __shared__ float selv[64];
    __shared__ int   seli[64];
    __shared__ float resv[64];
    __shared__ float redm[4];
    __shared__ __align__(16) float orow[H_];

    int row = blockIdx.x;
    int t = threadIdx.x;
    int lane = t & 63, wid = t >> 6;

    if (wid != 0) {
        for (int i = t - 64; i < H_; i += 192)
            orow[i] = outs[(size_t)row * H_ + i];
    } else {
        float cv[4]; int ci[4];
#pragma unroll
        for (int q = 0; q < 4; ++q) {
            size_t o = (size_t)row * 256 + q * 64 + lane;
            cv[q] = candV[o];
            ci[q] = candI[o];
        }
        float lv = cv[0]; int lix = ci[0]; int ls = 0;
#pragma unroll
        for (int q = 1; q < 4; ++q)
            if (cv[q] > lv || (cv[q] == lv && ci[q] < lix)) { lv = cv[q]; lix = ci[q]; ls = q; }

#pragma unroll 1
        for (int r = 0; r < 64; ++r) {
            float bv = lv; int bi = lix;
#pragma unroll
            for (int m = 1; m < 64; m <<= 1) {
                float ov = __shfl_xor(bv, m);
                int   oi = __shfl_xor(bi, m);
                if (ov > bv || (ov == bv && oi < bi)) { bv = ov; bi = oi; }
            }
            if (lane == r) { selv[r] = bv; seli[r] = bi; }
            if (lix == bi) {
#pragma unroll
                for (int q = 0; q < 4; ++q) cv[q] = (ls == q) ? NEG7 : cv[q];
                lv = cv[0]; lix = ci[0]; ls = 0;
#pragma unroll
                for (int q = 1; q < 4; ++q)
                    if (cv[q] > lv || (cv[q] == lv && ci[q] < lix)) { lv = cv[q]; lix = ci[q]; ls = q; }
            }
        }
    }
    __syncthreads();

    {
        float ms = fabsf(orow[t]) + fabsf(orow[t + 256]);
#pragma unroll
        for (int m = 1; m < 64; m <<= 1) ms += __shfl_xor(ms, m);
        if (lane == 0) redm[wid] = ms;
    }

    {
        int c = t >> 2, q = t & 3;
        int gidx = seli[c];
        const float4* w4 = (const float4*)(W + (size_t)gidx * H_);
        const float4* o4 = (const float4*)orow;
        double acc = 0.0;
#pragma unroll 8
        for (int i2 = 0; i2 < 32; ++i2) {
            float4 wv4 = w4[i2 * 4 + q];
            float4 ov4 = o4[i2 * 4 + q];
            acc += (double)wv4.x * (double)ov4.x + (double)wv4.y * (double)ov4.y
                 + (double)wv4.z * (double)ov4.z + (double)wv4.w * (double)ov4.w;
        }
        acc += __shfl_xor(acc, 1);
        acc += __shfl_xor(acc, 2);
        if (q == 0) resv[c] = (float)(acc + (double)bo[gidx]);
    }
    __syncthreads();

    if (t == 0)
        mOut[row] = (redm[0] + redm[1] + redm[2] + redm[3] > 0.f) ? 1.f : 0.f;

    if (t < 64) {
        float v = resv[t];
        int idx = seli[t];
#pragma unroll 1
        for (int r = 0; r < MV_; ++r) {
            float bv = v; int bi = idx;
#pragma unroll
            for (int m = 1; m < 64; m <<= 1) {
                float ov = __shfl_xor(bv, m);
                int   oi = __shfl_xor(bi, m);
                if (ov > bv || (ov == bv && oi < bi)) { bv = ov; bi = oi; }
            }
            if (t == 0)
                sOut[(size_t)row * MV_ + r] = (bv <= 0.0f) ? 0.0f : (float)bi;
            if (idx == bi) v = NEG7;
        }
    }
}

// ---------------------------------------------------------------------------
extern "C" void kernel_launch(void* const* d_in, const int* in_sizes, int n_in,
                              void* d_out, int out_size, void* d_ws, size_t ws_size,
                              hipStream_t stream) {
    const float* z      = (const float*)d_in[0];
    const int*   seq    = (const int*)d_in[1];
    const int*   length = (const int*)d_in[2];
    const float* Ew     = (const float*)d_in[3];
    const float* W_l2h  = (const float*)d_in[4];
    const float* b_l2h  = (const float*)d_in[5];
    const float* W_ih   = (const float*)d_in[6];
    const float* W_hh   = (const float*)d_in[7];
    const float* b_ih   = (const float*)d_in[8];
    const float* b_hh   = (const float*)d_in[9];
    const float* W_out  = (const float*)d_in[10];
    const float* b_out  = (const float*)d_in[11];

    float* out = (float*)d_out;

    double* emb_d = (double*)d_ws;               // 2048*256 f64 (A16 overlay after k4)
    double* gi_d  = emb_d + 524288;              // 2048*1536 f64 (W16 overlay after k4)
    double* hstep = gi_d + 3145728;              // 64 x 16384 f64 per-step h buffers (8MB)
    float*  outs  = (float*)(hstep + 1048576);   // 2048*512 f32
    float*  candV = outs + 1048576;              // 2048*256 f32
    int*    candI = (int*)(candV + (size_t)BS_ * 256);   // 2048*256 i32
    short*  A16   = (short*)emb_d;               // 2048*512 bf16 (emb dead after k4)
    short*  W16   = (short*)gi_d;                // 20000*512 bf16 (gi dead after k4)

    float* pOut = out;                           // 2048*20000
    float* sOut = out + (size_t)BS_ * V_;        // 2048*30
    float* mOut = sOut + (size_t)BS_ * MV_;      // 2048

    k12<<<BS_ + 64 + 1008, 256, 0, stream>>>(seq, Ew, z, W_l2h, b_l2h, emb_d, hstep);
    k3_gi<<<dim3(24, 32), 256, 0, stream>>>(emb_d, W_ih, b_ih, gi_d);
    k4_gru<<<NB4, 256, 0, stream>>>(gi_d, W_hh, b_hh, length, hstep, outs);
    k_prep2<<<5512, 256, 0, stream>>>(W_out, outs, W16, A16);
    k5_mfma<<<2512, 256, 0, stream>>>(A16, W16, b_out, pOut);
    k7a_cand<<<BS_, 512, 0, stream>>>(pOut, candV, candI);
    k7b_final<<<BS_, 256, 0, stream>>>(candV, candI, outs, W_out, b_out, mOut, sOut);
}